// Round 3
// baseline (1199.633 us; speedup 1.0000x reference)
//
#include <hip/hip_runtime.h>

#define H 128

typedef __bf16 bf8_t __attribute__((ext_vector_type(8)));
typedef float  f4_t  __attribute__((ext_vector_type(4)));

#define MFMA16(a, b, c) __builtin_amdgcn_mfma_f32_16x16x32_bf16((a), (b), (c), 0, 0, 0)

__device__ __forceinline__ float silu_f(float v) {
    return v * (1.0f / (1.0f + __expf(-v)));
}

__device__ __forceinline__ float wload(const void* p, int idx, bool f32) {
    return f32 ? ((const float*)p)[idx] : (float)((const __bf16*)p)[idx];
}

__device__ __forceinline__ bf8_t hload8(const void* p, size_t off, bool f32) {
    bf8_t v;
    if (f32) {
        const float4* q = (const float4*)((const float*)p + off);
        const float4 a = q[0], b = q[1];
        v[0]=(__bf16)a.x; v[1]=(__bf16)a.y; v[2]=(__bf16)a.z; v[3]=(__bf16)a.w;
        v[4]=(__bf16)b.x; v[5]=(__bf16)b.y; v[6]=(__bf16)b.z; v[7]=(__bf16)b.w;
    } else {
        v = *(const bf8_t*)((const __bf16*)p + off);
    }
    return v;
}

// ---------------------------------------------------------------------------
// dtype detection (f32 vs bf16 floats; int64 vs int32 edge_index)
// ---------------------------------------------------------------------------
__global__ void detect_kernel(const unsigned short* __restrict__ hraw,
                              const int* __restrict__ eiraw, int* __restrict__ flags)
{
    __shared__ int s_nf, s_oddnz;
    if (threadIdx.x == 0) { s_nf = 0; s_oddnz = 0; }
    __syncthreads();
    int nf = 0;
    for (int i = threadIdx.x; i < 16384; i += blockDim.x) {
        const unsigned short u = hraw[i];
        if (((u >> 7) & 0xFF) == 0xFF) nf++;
    }
    int onz = 0;
    for (int i = threadIdx.x; i < 512; i += blockDim.x) {
        if (eiraw[2*i + 1] != 0) onz++;
    }
    if (nf)  atomicAdd(&s_nf, nf);
    if (onz) atomicAdd(&s_oddnz, onz);
    __syncthreads();
    if (threadIdx.x == 0) {
        flags[0] = (s_nf > 0) ? 1 : 0;
        flags[1] = (s_oddnz == 0) ? 1 : 0;
    }
}

__global__ void cvt_ei_kernel(const void* __restrict__ src, int* __restrict__ dst,
                              int n, const int* __restrict__ flags)
{
    const int i = blockIdx.x*blockDim.x + threadIdx.x;
    if (i >= n) return;
    dst[i] = flags[1] ? (int)((const long long*)src)[i] : ((const int*)src)[i];
}

// ---------------------------------------------------------------------------
// CSR build: histogram -> 3-kernel scan -> scatter positions
// ---------------------------------------------------------------------------
__global__ void hist_kernel(const int* __restrict__ ei, int* __restrict__ cnt, int Ee)
{
    const int e = blockIdx.x*blockDim.x + threadIdx.x;
    if (e < Ee) atomicAdd(&cnt[ei[Ee + e]], 1);
}

__global__ void scanA_kernel(const int* __restrict__ cnt, int* __restrict__ bsum, int Nn)
{
    __shared__ int s[512];
    const int gi = blockIdx.x*512 + threadIdx.x;
    s[threadIdx.x] = (gi < Nn) ? cnt[gi] : 0;
    __syncthreads();
    for (int off = 256; off > 0; off >>= 1) {
        if (threadIdx.x < off) s[threadIdx.x] += s[threadIdx.x + off];
        __syncthreads();
    }
    if (threadIdx.x == 0) bsum[blockIdx.x] = s[0];
}

__global__ void scanB_kernel(int* __restrict__ bsum, int* __restrict__ base, int nCh)
{
    if (threadIdx.x == 0) {
        int acc = 0;
        for (int b = 0; b < nCh; ++b) { base[b] = acc; acc += bsum[b]; }
    }
}

__global__ void scanC_kernel(const int* __restrict__ cnt, const int* __restrict__ base,
                             int* __restrict__ off, int* __restrict__ cursor, int Nn)
{
    __shared__ int s[512];
    const int i  = threadIdx.x;
    const int gi = blockIdx.x*512 + i;
    const int v  = (gi < Nn) ? cnt[gi] : 0;
    s[i] = v;
    __syncthreads();
    for (int o = 1; o < 512; o <<= 1) {
        const int t = (i >= o) ? s[i - o] : 0;
        __syncthreads();
        s[i] += t;
        __syncthreads();
    }
    const int excl = s[i] - v;
    if (gi <= Nn) {
        const int val = base[blockIdx.x] + excl;
        off[gi] = val;
        if (gi < Nn) cursor[gi] = val;
    }
}

__global__ void scatter_kernel(const int* __restrict__ ei, int* __restrict__ cursor,
                               int* __restrict__ pos, int* __restrict__ srcs, int Ee)
{
    const int e = blockIdx.x*blockDim.x + threadIdx.x;
    if (e >= Ee) return;
    const int d = ei[Ee + e];
    const int p = atomicAdd(&cursor[d], 1);
    pos[e] = p;
    srcs[p] = ei[e];
}

// ---------------------------------------------------------------------------
// Edge kernel (CSR variant): fused edge MLP, writes m_ij to its sorted slot
// (streaming, no atomics) and coord weight to cw_buf.
// ---------------------------------------------------------------------------
__global__ __launch_bounds__(512, 2)
void egnn_edge_csr_kernel(const void* __restrict__ h, const void* __restrict__ x,
                          const int* __restrict__ ei, const int* __restrict__ pos_arr,
                          const void* __restrict__ We1, const void* __restrict__ be1,
                          const void* __restrict__ We2, const void* __restrict__ be2,
                          const void* __restrict__ Wc1, const void* __restrict__ bc1,
                          const void* __restrict__ Wc2, const int* __restrict__ flags,
                          __bf16* __restrict__ m_buf, float* __restrict__ cw_buf,
                          int Nn, int Ee)
{
    const bool f32 = flags[0] != 0;
    const int tid  = threadIdx.x;
    const int wv   = tid >> 6;
    const int lane = tid & 63;
    const int quad = lane >> 4;
    const int l15  = lane & 15;
    const int mg   = wv >> 2;
    const int ng   = wv & 3;

    bf8_t bW1[8][2];
    bf8_t bW2[4][2];
    bf8_t bWc[4][2];
    float be1v[2], be2v[2], bc1v[2], w1dv[2], wc2v[2];
    #pragma unroll
    for (int t = 0; t < 2; ++t) {
        const int n = ng*32 + t*16 + l15;
        #pragma unroll
        for (int kc = 0; kc < 8; ++kc) {
            bf8_t v;
            #pragma unroll
            for (int j = 0; j < 8; ++j) v[j] = (__bf16)wload(We1, (kc*32 + quad*8 + j)*H + n, f32);
            bW1[kc][t] = v;
        }
        #pragma unroll
        for (int kc = 0; kc < 4; ++kc) {
            bf8_t v, u;
            #pragma unroll
            for (int j = 0; j < 8; ++j) {
                v[j] = (__bf16)wload(We2, (kc*32 + quad*8 + j)*H + n, f32);
                u[j] = (__bf16)wload(Wc1, (kc*32 + quad*8 + j)*H + n, f32);
            }
            bW2[kc][t] = v;
            bWc[kc][t] = u;
        }
        be1v[t] = wload(be1, n, f32);
        be2v[t] = wload(be2, n, f32);
        bc1v[t] = wload(bc1, n, f32);
        w1dv[t] = wload(We1, 256*H + n, f32);
        wc2v[t] = wload(Wc2, n, f32);
    }

    __shared__ __bf16 s_in[32*264];
    __shared__ __bf16 s_m1[32*136];
    __shared__ __bf16 s_m2[32*136];
    __shared__ float  s_dist[32];
    __shared__ int    s_pos[32];
    __shared__ float  s_cw[32*4];

    const int tiles = Ee >> 5;
    for (int tile = blockIdx.x; tile < tiles; tile += gridDim.x) {
        const int ebase = tile << 5;
        __syncthreads();

        if (tid < 32) {
            const int e  = ebase + tid;
            const int sn = ei[e];
            const int dn = ei[Ee + e];
            s_pos[tid] = pos_arr[e];
            float d2 = 0.f;
            #pragma unroll
            for (int c = 0; c < 3; ++c) {
                float r;
                if (f32) r = ((const float*)x)[sn*3 + c] - ((const float*)x)[dn*3 + c];
                else     r = (float)((const __bf16*)x)[sn*3 + c] - (float)((const __bf16*)x)[dn*3 + c];
                d2 += r*r;
            }
            s_dist[tid] = d2;
        }
        #pragma unroll
        for (int r = 0; r < 2; ++r) {
            const int idx = tid + r*512;
            const int m = idx >> 5, c = idx & 31;
            const int e = ebase + m;
            const int node = (c < 16) ? ei[e] : ei[Ee + e];
            *(bf8_t*)&s_in[m*264 + c*8] = hload8(h, (size_t)node*H + (c & 15)*8, f32);
        }
        __syncthreads();

        // layer 1
        {
            f4_t a0 = {0.f,0.f,0.f,0.f}, a1 = {0.f,0.f,0.f,0.f};
            const int abase = (mg*16 + l15)*264 + quad*8;
            #pragma unroll
            for (int kc = 0; kc < 8; ++kc) {
                const bf8_t a = *(const bf8_t*)&s_in[abase + kc*32];
                a0 = MFMA16(a, bW1[kc][0], a0);
                a1 = MFMA16(a, bW1[kc][1], a1);
            }
            #pragma unroll
            for (int i = 0; i < 4; ++i) {
                const int m = mg*16 + quad*4 + i;
                const float d2 = s_dist[m];
                s_m1[m*136 + ng*32 + l15]      = (__bf16)silu_f(a0[i] + d2*w1dv[0] + be1v[0]);
                s_m1[m*136 + ng*32 + 16 + l15] = (__bf16)silu_f(a1[i] + d2*w1dv[1] + be1v[1]);
            }
        }
        __syncthreads();

        // layer 2 (m_ij)
        {
            f4_t a0 = {0.f,0.f,0.f,0.f}, a1 = {0.f,0.f,0.f,0.f};
            const int abase = (mg*16 + l15)*136 + quad*8;
            #pragma unroll
            for (int kc = 0; kc < 4; ++kc) {
                const bf8_t a = *(const bf8_t*)&s_m1[abase + kc*32];
                a0 = MFMA16(a, bW2[kc][0], a0);
                a1 = MFMA16(a, bW2[kc][1], a1);
            }
            #pragma unroll
            for (int i = 0; i < 4; ++i) {
                const int m = mg*16 + quad*4 + i;
                s_m2[m*136 + ng*32 + l15]      = (__bf16)silu_f(a0[i] + be2v[0]);
                s_m2[m*136 + ng*32 + 16 + l15] = (__bf16)silu_f(a1[i] + be2v[1]);
            }
        }
        __syncthreads();

        // layer 3: coord head
        {
            f4_t a0 = {0.f,0.f,0.f,0.f}, a1 = {0.f,0.f,0.f,0.f};
            const int abase = (mg*16 + l15)*136 + quad*8;
            #pragma unroll
            for (int kc = 0; kc < 4; ++kc) {
                const bf8_t a = *(const bf8_t*)&s_m2[abase + kc*32];
                a0 = MFMA16(a, bWc[kc][0], a0);
                a1 = MFMA16(a, bWc[kc][1], a1);
            }
            float p[4];
            #pragma unroll
            for (int i = 0; i < 4; ++i) {
                const float v0 = silu_f(a0[i] + bc1v[0]);
                const float v1 = silu_f(a1[i] + bc1v[1]);
                p[i] = v0*wc2v[0] + v1*wc2v[1];
            }
            #pragma unroll
            for (int off = 1; off < 16; off <<= 1) {
                #pragma unroll
                for (int i = 0; i < 4; ++i) p[i] += __shfl_xor(p[i], off, 64);
            }
            if (l15 == 0) {
                #pragma unroll
                for (int i = 0; i < 4; ++i)
                    s_cw[(mg*16 + quad*4 + i)*4 + ng] = p[i];
            }
        }
        __syncthreads();

        // streaming stores to sorted slots
        {
            const int m = tid >> 4, c = tid & 15;
            *(bf8_t*)(m_buf + (size_t)s_pos[m]*H + c*8) = *(const bf8_t*)&s_m2[m*136 + c*8];
        }
        if (tid < 32) {
            cw_buf[s_pos[tid]] = s_cw[tid*4] + s_cw[tid*4+1] + s_cw[tid*4+2] + s_cw[tid*4+3];
        }
    }
}

// ---------------------------------------------------------------------------
// Aggregation: one wave per node. Sequential (coalesced) read of sorted m_buf,
// recompute rel_pos, write msg_agg (f32) and x_out.
// ---------------------------------------------------------------------------
__global__ __launch_bounds__(512)
void egnn_agg_kernel(const void* __restrict__ x, const int* __restrict__ off,
                     const int* __restrict__ srcs, const __bf16* __restrict__ m_buf,
                     const float* __restrict__ cw_buf, float* __restrict__ msg_agg,
                     const int* __restrict__ flags, void* __restrict__ out,
                     size_t obase, int Nn)
{
    const bool f32 = flags[0] != 0;
    const int wv = threadIdx.x >> 6, lane = threadIdx.x & 63;
    const int n = blockIdx.x*8 + wv;
    if (n >= Nn) return;
    const int p0 = off[n], p1 = off[n+1];

    float xd0, xd1, xd2;
    if (f32) { const float* xp = (const float*)x + (size_t)n*3; xd0=xp[0]; xd1=xp[1]; xd2=xp[2]; }
    else     { const __bf16* xp = (const __bf16*)x + (size_t)n*3; xd0=(float)xp[0]; xd1=(float)xp[1]; xd2=(float)xp[2]; }

    float ms0 = 0.f, ms1 = 0.f, c0 = 0.f, c1 = 0.f, c2 = 0.f;
    const unsigned int* mb = (const unsigned int*)m_buf;
    for (int p = p0; p < p1; ++p) {
        const unsigned int u = mb[(size_t)p*64 + lane];
        ms0 += __uint_as_float(u << 16);
        ms1 += __uint_as_float(u & 0xffff0000u);
        const float cw = cw_buf[p];
        const int sn = srcs[p];
        float xs0, xs1, xs2;
        if (f32) { const float* xp = (const float*)x + (size_t)sn*3; xs0=xp[0]; xs1=xp[1]; xs2=xp[2]; }
        else     { const __bf16* xp = (const __bf16*)x + (size_t)sn*3; xs0=(float)xp[0]; xs1=(float)xp[1]; xs2=(float)xp[2]; }
        c0 += (xs0 - xd0)*cw;
        c1 += (xs1 - xd1)*cw;
        c2 += (xs2 - xd2)*cw;
    }
    float2 st; st.x = ms0; st.y = ms1;
    *(float2*)&msg_agg[(size_t)n*H + 2*lane] = st;
    if (lane == 0) {
        const float o0 = xd0 + c0, o1 = xd1 + c1, o2 = xd2 + c2;
        if (f32) {
            float* op = (float*)out + obase + (size_t)n*3;
            op[0] = o0; op[1] = o1; op[2] = o2;
        } else {
            __bf16* op = (__bf16*)out + obase + (size_t)n*3;
            op[0] = (__bf16)o0; op[1] = (__bf16)o1; op[2] = (__bf16)o2;
        }
    }
}

// ---------------------------------------------------------------------------
// Fallback edge kernel (atomic path, proven in round 2)
// ---------------------------------------------------------------------------
__global__ __launch_bounds__(512, 2)
void egnn_edge_kernel(const void* __restrict__ h, const void* __restrict__ x,
                      const int* __restrict__ ei,
                      const void* __restrict__ We1, const void* __restrict__ be1,
                      const void* __restrict__ We2, const void* __restrict__ be2,
                      const void* __restrict__ Wc1, const void* __restrict__ bc1,
                      const void* __restrict__ Wc2, const int* __restrict__ flags,
                      float* __restrict__ msg_agg, float* __restrict__ coord_agg,
                      int Nn, int Ee)
{
    const bool f32 = flags[0] != 0;
    const int tid  = threadIdx.x;
    const int wv   = tid >> 6;
    const int lane = tid & 63;
    const int quad = lane >> 4;
    const int l15  = lane & 15;
    const int mg   = wv >> 2;
    const int ng   = wv & 3;

    bf8_t bW1[8][2];
    bf8_t bW2[4][2];
    bf8_t bWc[4][2];
    float be1v[2], be2v[2], bc1v[2], w1dv[2], wc2v[2];
    #pragma unroll
    for (int t = 0; t < 2; ++t) {
        const int n = ng*32 + t*16 + l15;
        #pragma unroll
        for (int kc = 0; kc < 8; ++kc) {
            bf8_t v;
            #pragma unroll
            for (int j = 0; j < 8; ++j) v[j] = (__bf16)wload(We1, (kc*32 + quad*8 + j)*H + n, f32);
            bW1[kc][t] = v;
        }
        #pragma unroll
        for (int kc = 0; kc < 4; ++kc) {
            bf8_t v, u;
            #pragma unroll
            for (int j = 0; j < 8; ++j) {
                v[j] = (__bf16)wload(We2, (kc*32 + quad*8 + j)*H + n, f32);
                u[j] = (__bf16)wload(Wc1, (kc*32 + quad*8 + j)*H + n, f32);
            }
            bW2[kc][t] = v;
            bWc[kc][t] = u;
        }
        be1v[t] = wload(be1, n, f32);
        be2v[t] = wload(be2, n, f32);
        bc1v[t] = wload(bc1, n, f32);
        w1dv[t] = wload(We1, 256*H + n, f32);
        wc2v[t] = wload(Wc2, n, f32);
    }

    __shared__ __bf16 s_in[32*264];
    __shared__ __bf16 s_m1[32*136];
    __shared__ __bf16 s_m2[32*136];
    __shared__ float  s_rel[32*3];
    __shared__ float  s_dist[32];
    __shared__ int    s_dstv[32];
    __shared__ float  s_cw[32*4];

    const int tiles = Ee >> 5;
    for (int tile = blockIdx.x; tile < tiles; tile += gridDim.x) {
        const int ebase = tile << 5;
        __syncthreads();

        if (tid < 32) {
            const int e  = ebase + tid;
            const int sn = ei[e];
            const int dn = ei[Ee + e];
            s_dstv[tid] = dn;
            float d2 = 0.f;
            #pragma unroll
            for (int c = 0; c < 3; ++c) {
                float r;
                if (f32) r = ((const float*)x)[sn*3 + c] - ((const float*)x)[dn*3 + c];
                else     r = (float)((const __bf16*)x)[sn*3 + c] - (float)((const __bf16*)x)[dn*3 + c];
                s_rel[tid*3 + c] = r;
                d2 += r*r;
            }
            s_dist[tid] = d2;
        }
        #pragma unroll
        for (int r = 0; r < 2; ++r) {
            const int idx = tid + r*512;
            const int m = idx >> 5, c = idx & 31;
            const int e = ebase + m;
            const int node = (c < 16) ? ei[e] : ei[Ee + e];
            *(bf8_t*)&s_in[m*264 + c*8] = hload8(h, (size_t)node*H + (c & 15)*8, f32);
        }
        __syncthreads();

        {
            f4_t a0 = {0.f,0.f,0.f,0.f}, a1 = {0.f,0.f,0.f,0.f};
            const int abase = (mg*16 + l15)*264 + quad*8;
            #pragma unroll
            for (int kc = 0; kc < 8; ++kc) {
                const bf8_t a = *(const bf8_t*)&s_in[abase + kc*32];
                a0 = MFMA16(a, bW1[kc][0], a0);
                a1 = MFMA16(a, bW1[kc][1], a1);
            }
            #pragma unroll
            for (int i = 0; i < 4; ++i) {
                const int m = mg*16 + quad*4 + i;
                const float d2 = s_dist[m];
                s_m1[m*136 + ng*32 + l15]      = (__bf16)silu_f(a0[i] + d2*w1dv[0] + be1v[0]);
                s_m1[m*136 + ng*32 + 16 + l15] = (__bf16)silu_f(a1[i] + d2*w1dv[1] + be1v[1]);
            }
        }
        __syncthreads();

        {
            f4_t a0 = {0.f,0.f,0.f,0.f}, a1 = {0.f,0.f,0.f,0.f};
            const int abase = (mg*16 + l15)*136 + quad*8;
            #pragma unroll
            for (int kc = 0; kc < 4; ++kc) {
                const bf8_t a = *(const bf8_t*)&s_m1[abase + kc*32];
                a0 = MFMA16(a, bW2[kc][0], a0);
                a1 = MFMA16(a, bW2[kc][1], a1);
            }
            #pragma unroll
            for (int i = 0; i < 4; ++i) {
                const int m = mg*16 + quad*4 + i;
                const float v0 = silu_f(a0[i] + be2v[0]);
                const float v1 = silu_f(a1[i] + be2v[1]);
                s_m2[m*136 + ng*32 + l15]      = (__bf16)v0;
                s_m2[m*136 + ng*32 + 16 + l15] = (__bf16)v1;
                const size_t db = (size_t)s_dstv[m]*H + ng*32 + l15;
                atomicAdd(&msg_agg[db],      v0);
                atomicAdd(&msg_agg[db + 16], v1);
            }
        }
        __syncthreads();

        {
            f4_t a0 = {0.f,0.f,0.f,0.f}, a1 = {0.f,0.f,0.f,0.f};
            const int abase = (mg*16 + l15)*136 + quad*8;
            #pragma unroll
            for (int kc = 0; kc < 4; ++kc) {
                const bf8_t a = *(const bf8_t*)&s_m2[abase + kc*32];
                a0 = MFMA16(a, bWc[kc][0], a0);
                a1 = MFMA16(a, bWc[kc][1], a1);
            }
            float p[4];
            #pragma unroll
            for (int i = 0; i < 4; ++i) {
                const float v0 = silu_f(a0[i] + bc1v[0]);
                const float v1 = silu_f(a1[i] + bc1v[1]);
                p[i] = v0*wc2v[0] + v1*wc2v[1];
            }
            #pragma unroll
            for (int off = 1; off < 16; off <<= 1) {
                #pragma unroll
                for (int i = 0; i < 4; ++i) p[i] += __shfl_xor(p[i], off, 64);
            }
            if (l15 == 0) {
                #pragma unroll
                for (int i = 0; i < 4; ++i)
                    s_cw[(mg*16 + quad*4 + i)*4 + ng] = p[i];
            }
        }
        __syncthreads();

        if (tid < 96) {
            const int m = tid / 3, c = tid - m*3;
            const float cw = s_cw[m*4 + 0] + s_cw[m*4 + 1] + s_cw[m*4 + 2] + s_cw[m*4 + 3];
            atomicAdd(&coord_agg[(size_t)s_dstv[m]*3 + c], s_rel[m*3 + c]*cw);
        }
    }
}

// ---------------------------------------------------------------------------
// Node kernel: h_out = h + silu([h | msg_agg] @ Wn1 + bn1) @ Wn2 + bn2
// ---------------------------------------------------------------------------
__global__ __launch_bounds__(512, 2)
void egnn_node_kernel(const void* __restrict__ h, const float* __restrict__ msg_agg,
                      const void* __restrict__ Wn1, const void* __restrict__ bn1,
                      const void* __restrict__ Wn2, const void* __restrict__ bn2,
                      const int* __restrict__ flags, void* __restrict__ h_out, int Nn)
{
    const bool f32 = flags[0] != 0;
    const int tid  = threadIdx.x;
    const int wv   = tid >> 6;
    const int lane = tid & 63;
    const int quad = lane >> 4;
    const int l15  = lane & 15;
    const int mg   = wv >> 2;
    const int ng   = wv & 3;

    bf8_t bW1[8][2];
    bf8_t bW2[4][2];
    float b1v[2], b2v[2];
    #pragma unroll
    for (int t = 0; t < 2; ++t) {
        const int n = ng*32 + t*16 + l15;
        #pragma unroll
        for (int kc = 0; kc < 8; ++kc) {
            bf8_t v;
            #pragma unroll
            for (int j = 0; j < 8; ++j) v[j] = (__bf16)wload(Wn1, (kc*32 + quad*8 + j)*H + n, f32);
            bW1[kc][t] = v;
        }
        #pragma unroll
        for (int kc = 0; kc < 4; ++kc) {
            bf8_t v;
            #pragma unroll
            for (int j = 0; j < 8; ++j) v[j] = (__bf16)wload(Wn2, (kc*32 + quad*8 + j)*H + n, f32);
            bW2[kc][t] = v;
        }
        b1v[t] = wload(bn1, n, f32);
        b2v[t] = wload(bn2, n, f32);
    }

    __shared__ __bf16 s_in[32*264];
    __shared__ __bf16 s_t1[32*136];

    const int tiles = (Nn + 31) >> 5;
    for (int tile = blockIdx.x; tile < tiles; tile += gridDim.x) {
        const int nb = tile << 5;
        __syncthreads();
        #pragma unroll
        for (int r = 0; r < 2; ++r) {
            const int idx = tid + r*512;
            const int m = idx >> 5, c = idx & 31;
            int node = nb + m;
            if (node >= Nn) node = Nn - 1;
            if (c < 16) {
                *(bf8_t*)&s_in[m*264 + c*8] = hload8(h, (size_t)node*H + c*8, f32);
            } else {
                const float4* mp = (const float4*)(msg_agg + (size_t)node*H + (c - 16)*8);
                const float4 v0 = mp[0], v1 = mp[1];
                __bf16* d = &s_in[m*264 + c*8];
                d[0] = (__bf16)v0.x; d[1] = (__bf16)v0.y; d[2] = (__bf16)v0.z; d[3] = (__bf16)v0.w;
                d[4] = (__bf16)v1.x; d[5] = (__bf16)v1.y; d[6] = (__bf16)v1.z; d[7] = (__bf16)v1.w;
            }
        }
        __syncthreads();

        {
            f4_t a0 = {0.f,0.f,0.f,0.f}, a1 = {0.f,0.f,0.f,0.f};
            const int abase = (mg*16 + l15)*264 + quad*8;
            #pragma unroll
            for (int kc = 0; kc < 8; ++kc) {
                const bf8_t a = *(const bf8_t*)&s_in[abase + kc*32];
                a0 = MFMA16(a, bW1[kc][0], a0);
                a1 = MFMA16(a, bW1[kc][1], a1);
            }
            #pragma unroll
            for (int i = 0; i < 4; ++i) {
                const int m = mg*16 + quad*4 + i;
                s_t1[m*136 + ng*32 + l15]      = (__bf16)silu_f(a0[i] + b1v[0]);
                s_t1[m*136 + ng*32 + 16 + l15] = (__bf16)silu_f(a1[i] + b1v[1]);
            }
        }
        __syncthreads();

        {
            f4_t a0 = {0.f,0.f,0.f,0.f}, a1 = {0.f,0.f,0.f,0.f};
            const int abase = (mg*16 + l15)*136 + quad*8;
            #pragma unroll
            for (int kc = 0; kc < 4; ++kc) {
                const bf8_t a = *(const bf8_t*)&s_t1[abase + kc*32];
                a0 = MFMA16(a, bW2[kc][0], a0);
                a1 = MFMA16(a, bW2[kc][1], a1);
            }
            #pragma unroll
            for (int i = 0; i < 4; ++i) {
                const int node = nb + mg*16 + quad*4 + i;
                if (node < Nn) {
                    const int n0 = ng*32 + l15, n1 = n0 + 16;
                    const size_t i0 = (size_t)node*H + n0, i1 = (size_t)node*H + n1;
                    const float h0 = f32 ? ((const float*)h)[i0] : (float)((const __bf16*)h)[i0];
                    const float h1 = f32 ? ((const float*)h)[i1] : (float)((const __bf16*)h)[i1];
                    const float o0 = a0[i] + b2v[0] + h0;
                    const float o1 = a1[i] + b2v[1] + h1;
                    if (f32) {
                        ((float*)h_out)[i0] = o0;
                        ((float*)h_out)[i1] = o1;
                    } else {
                        ((__bf16*)h_out)[i0] = (__bf16)o0;
                        ((__bf16*)h_out)[i1] = (__bf16)o1;
                    }
                }
            }
        }
    }
}

__global__ void egnn_x_kernel(const void* __restrict__ x, const float* __restrict__ coord_agg,
                              const int* __restrict__ flags, void* __restrict__ out,
                              size_t obase, int total)
{
    const bool f32 = flags[0] != 0;
    const int i = blockIdx.x*blockDim.x + threadIdx.x;
    if (i >= total) return;
    const float xv = f32 ? ((const float*)x)[i] : (float)((const __bf16*)x)[i];
    const float o = xv + coord_agg[i];
    if (f32) ((float*)out)[obase + i] = o;
    else     ((__bf16*)out)[obase + i] = (__bf16)o;
}

static inline size_t align256(size_t v) { return (v + 255) & ~(size_t)255; }

extern "C" void kernel_launch(void* const* d_in, const int* in_sizes, int n_in,
                              void* d_out, int out_size, void* d_ws, size_t ws_size,
                              hipStream_t stream)
{
    const void* h   = d_in[0];
    const void* x   = d_in[1];
    const void* ei0 = d_in[2];
    const void* We1 = d_in[3];
    const void* be1 = d_in[4];
    const void* We2 = d_in[5];
    const void* be2 = d_in[6];
    const void* Wc1 = d_in[7];
    const void* bc1 = d_in[8];
    const void* Wc2 = d_in[9];
    const void* Wn1 = d_in[10];
    const void* bn1 = d_in[11];
    const void* Wn2 = d_in[12];
    const void* bn2 = d_in[13];

    const int Nn = in_sizes[0] / H;   // 50000
    const int Ee = in_sizes[2] / 2;   // 640000

    // ---- CSR-path workspace layout ----
    char* ws = (char*)d_ws;
    size_t o = 0;
    size_t o_mbuf  = o; o = align256(o + (size_t)Ee*H*2);        // m_ij bf16, sorted order
    size_t o_msg   = o; o = align256(o + (size_t)Nn*H*4);        // msg_agg f32
    size_t o_ei    = o; o = align256(o + (size_t)2*Ee*4);        // canonical edge_index
    size_t o_pos   = o; o = align256(o + (size_t)Ee*4);          // pos[e]
    size_t o_srcs  = o; o = align256(o + (size_t)Ee*4);          // srcs[p]
    size_t o_cw    = o; o = align256(o + (size_t)Ee*4);          // cw_buf[p]
    size_t o_cnt   = o; o = align256(o + (size_t)Nn*4);
    size_t o_off   = o; o = align256(o + (size_t)(Nn+1)*4);
    size_t o_cur   = o; o = align256(o + (size_t)Nn*4);
    size_t o_bsum  = o; o = align256(o + 512*4);
    size_t o_base  = o; o = align256(o + 512*4);
    size_t o_flags = o; o = align256(o + 64);
    const size_t need_csr = o;

    const int nCh = (Nn + 1 + 511) / 512;

    if (ws_size >= need_csr) {
        __bf16* m_buf   = (__bf16*)(ws + o_mbuf);
        float*  msg_agg = (float*) (ws + o_msg);
        int*    ei      = (int*)   (ws + o_ei);
        int*    pos     = (int*)   (ws + o_pos);
        int*    srcs    = (int*)   (ws + o_srcs);
        float*  cw_buf  = (float*) (ws + o_cw);
        int*    cnt     = (int*)   (ws + o_cnt);
        int*    off     = (int*)   (ws + o_off);
        int*    cursor  = (int*)   (ws + o_cur);
        int*    bsum    = (int*)   (ws + o_bsum);
        int*    base    = (int*)   (ws + o_base);
        int*    flags   = (int*)   (ws + o_flags);

        detect_kernel<<<1, 256, 0, stream>>>((const unsigned short*)h, (const int*)ei0, flags);
        cvt_ei_kernel<<<(2*Ee + 511)/512, 512, 0, stream>>>(ei0, ei, 2*Ee, flags);
        hipMemsetAsync(cnt, 0, (size_t)Nn*4, stream);
        hist_kernel<<<(Ee + 511)/512, 512, 0, stream>>>(ei, cnt, Ee);
        scanA_kernel<<<nCh, 512, 0, stream>>>(cnt, bsum, Nn);
        scanB_kernel<<<1, 64, 0, stream>>>(bsum, base, nCh);
        scanC_kernel<<<nCh, 512, 0, stream>>>(cnt, base, off, cursor, Nn);
        scatter_kernel<<<(Ee + 511)/512, 512, 0, stream>>>(ei, cursor, pos, srcs, Ee);

        egnn_edge_csr_kernel<<<2048, 512, 0, stream>>>(h, x, ei, pos, We1, be1, We2, be2,
                                                       Wc1, bc1, Wc2, flags, m_buf, cw_buf, Nn, Ee);

        egnn_agg_kernel<<<(Nn + 7)/8, 512, 0, stream>>>(x, off, srcs, m_buf, cw_buf,
                                                        msg_agg, flags, d_out, (size_t)Nn*H, Nn);
        egnn_node_kernel<<<512, 512, 0, stream>>>(h, msg_agg, Wn1, bn1, Wn2, bn2,
                                                  flags, d_out, Nn);
    } else {
        // fallback: proven atomic path
        float* msg_agg   = (float*)ws;
        float* coord_agg = (float*)(ws + (size_t)Nn*H*4);
        int*   ei        = (int*)  (ws + (size_t)Nn*H*4 + (size_t)Nn*3*4);
        int*   flags     = (int*)  (ws + (size_t)Nn*H*4 + (size_t)Nn*3*4 + (size_t)2*Ee*4);

        detect_kernel<<<1, 256, 0, stream>>>((const unsigned short*)h, (const int*)ei0, flags);
        cvt_ei_kernel<<<(2*Ee + 255)/256, 256, 0, stream>>>(ei0, ei, 2*Ee, flags);
        hipMemsetAsync(msg_agg,   0, (size_t)Nn*H*4, stream);
        hipMemsetAsync(coord_agg, 0, (size_t)Nn*3*4, stream);
        egnn_edge_kernel<<<1024, 512, 0, stream>>>(h, x, ei, We1, be1, We2, be2,
                                                   Wc1, bc1, Wc2, flags,
                                                   msg_agg, coord_agg, Nn, Ee);
        egnn_node_kernel<<<512, 512, 0, stream>>>(h, msg_agg, Wn1, bn1, Wn2, bn2,
                                                  flags, d_out, Nn);
        egnn_x_kernel<<<(Nn*3 + 255)/256, 256, 0, stream>>>(x, coord_agg, flags, d_out,
                                                            (size_t)Nn*H, Nn*3);
    }
}

// Round 4
// 860.695 us; speedup vs baseline: 1.3938x; 1.3938x over previous
//
#include <hip/hip_runtime.h>

#define H 128

typedef __bf16 bf8_t __attribute__((ext_vector_type(8)));
typedef float  f4_t  __attribute__((ext_vector_type(4)));

#define MFMA16(a, b, c) __builtin_amdgcn_mfma_f32_16x16x32_bf16((a), (b), (c), 0, 0, 0)

__device__ __forceinline__ float silu_f(float v) {
    return v * (1.0f / (1.0f + __expf(-v)));
}

// LDS-only barrier: waits own-wave LDS ops, does NOT drain vmcnt, so global
// prefetch loads stay in flight across it. All cross-thread traffic in the
// edge kernel goes through LDS, so lgkmcnt(0)+barrier is sufficient.
__device__ __forceinline__ void bar_lds() {
    asm volatile("s_waitcnt lgkmcnt(0)\ns_barrier" ::: "memory");
}

__device__ __forceinline__ float wload(const void* p, int idx, bool f32) {
    return f32 ? ((const float*)p)[idx] : (float)((const __bf16*)p)[idx];
}

__device__ __forceinline__ bf8_t hload8(const void* p, size_t off, bool f32) {
    bf8_t v;
    if (f32) {
        const float4* q = (const float4*)((const float*)p + off);
        const float4 a = q[0], b = q[1];
        v[0]=(__bf16)a.x; v[1]=(__bf16)a.y; v[2]=(__bf16)a.z; v[3]=(__bf16)a.w;
        v[4]=(__bf16)b.x; v[5]=(__bf16)b.y; v[6]=(__bf16)b.z; v[7]=(__bf16)b.w;
    } else {
        v = *(const bf8_t*)((const __bf16*)p + off);
    }
    return v;
}

// ---------------------------------------------------------------------------
// dtype detection
// ---------------------------------------------------------------------------
__global__ void detect_kernel(const unsigned short* __restrict__ hraw,
                              const int* __restrict__ eiraw, int* __restrict__ flags)
{
    __shared__ int s_nf, s_oddnz;
    if (threadIdx.x == 0) { s_nf = 0; s_oddnz = 0; }
    __syncthreads();
    int nf = 0;
    for (int i = threadIdx.x; i < 16384; i += blockDim.x) {
        const unsigned short u = hraw[i];
        if (((u >> 7) & 0xFF) == 0xFF) nf++;
    }
    int onz = 0;
    for (int i = threadIdx.x; i < 512; i += blockDim.x) {
        if (eiraw[2*i + 1] != 0) onz++;
    }
    if (nf)  atomicAdd(&s_nf, nf);
    if (onz) atomicAdd(&s_oddnz, onz);
    __syncthreads();
    if (threadIdx.x == 0) {
        flags[0] = (s_nf > 0) ? 1 : 0;
        flags[1] = (s_oddnz == 0) ? 1 : 0;
    }
}

__global__ void cvt_ei_kernel(const void* __restrict__ src, int* __restrict__ dst,
                              int n, const int* __restrict__ flags)
{
    const int i = blockIdx.x*blockDim.x + threadIdx.x;
    if (i >= n) return;
    dst[i] = flags[1] ? (int)((const long long*)src)[i] : ((const int*)src)[i];
}

// ---------------------------------------------------------------------------
// CSR build
// ---------------------------------------------------------------------------
__global__ void hist_kernel(const int* __restrict__ ei, int* __restrict__ cnt, int Ee)
{
    const int e = blockIdx.x*blockDim.x + threadIdx.x;
    if (e < Ee) atomicAdd(&cnt[ei[Ee + e]], 1);
}

__global__ void scanA_kernel(const int* __restrict__ cnt, int* __restrict__ bsum, int Nn)
{
    __shared__ int s[512];
    const int gi = blockIdx.x*512 + threadIdx.x;
    s[threadIdx.x] = (gi < Nn) ? cnt[gi] : 0;
    __syncthreads();
    for (int off = 256; off > 0; off >>= 1) {
        if (threadIdx.x < off) s[threadIdx.x] += s[threadIdx.x + off];
        __syncthreads();
    }
    if (threadIdx.x == 0) bsum[blockIdx.x] = s[0];
}

__global__ void scanB_kernel(int* __restrict__ bsum, int* __restrict__ base, int nCh)
{
    if (threadIdx.x == 0) {
        int acc = 0;
        for (int b = 0; b < nCh; ++b) { base[b] = acc; acc += bsum[b]; }
    }
}

__global__ void scanC_kernel(const int* __restrict__ cnt, const int* __restrict__ base,
                             int* __restrict__ off, int* __restrict__ cursor, int Nn)
{
    __shared__ int s[512];
    const int i  = threadIdx.x;
    const int gi = blockIdx.x*512 + i;
    const int v  = (gi < Nn) ? cnt[gi] : 0;
    s[i] = v;
    __syncthreads();
    for (int o = 1; o < 512; o <<= 1) {
        const int t = (i >= o) ? s[i - o] : 0;
        __syncthreads();
        s[i] += t;
        __syncthreads();
    }
    const int excl = s[i] - v;
    if (gi <= Nn) {
        const int val = base[blockIdx.x] + excl;
        off[gi] = val;
        if (gi < Nn) cursor[gi] = val;
    }
}

__global__ void scatter_kernel(const int* __restrict__ ei, int* __restrict__ cursor,
                               int* __restrict__ srcs, int* __restrict__ dsts, int Ee)
{
    const int e = blockIdx.x*blockDim.x + threadIdx.x;
    if (e >= Ee) return;
    const int d = ei[Ee + e];
    const int p = atomicAdd(&cursor[d], 1);
    srcs[p] = ei[e];
    dsts[p] = d;
}

// ---------------------------------------------------------------------------
// Prep: h -> bf16 copy; per-sorted-slot geometry (rel, dist^2)
// ---------------------------------------------------------------------------
__global__ void cvt_h_kernel(const void* __restrict__ h, __bf16* __restrict__ hb,
                             const int* __restrict__ flags, int nchunks)
{
    const int i = blockIdx.x*blockDim.x + threadIdx.x;
    if (i >= nchunks) return;
    *(bf8_t*)(hb + (size_t)i*8) = hload8(h, (size_t)i*8, flags[0] != 0);
}

__global__ void prep_geom_kernel(const void* __restrict__ x, const int* __restrict__ srcs,
                                 const int* __restrict__ dsts, float4* __restrict__ rel4,
                                 const int* __restrict__ flags, int Ee)
{
    const int p = blockIdx.x*blockDim.x + threadIdx.x;
    if (p >= Ee) return;
    const bool f32 = flags[0] != 0;
    const int sn = srcs[p], dn = dsts[p];
    float r[3];
    #pragma unroll
    for (int c = 0; c < 3; ++c)
        r[c] = wload(x, sn*3 + c, f32) - wload(x, dn*3 + c, f32);
    float4 o; o.x = r[0]; o.y = r[1]; o.z = r[2];
    o.w = r[0]*r[0] + r[1]*r[1] + r[2]*r[2];
    rel4[p] = o;
}

// ---------------------------------------------------------------------------
// Edge kernel (pipelined, dst-sorted, no atomics): fused 3-layer edge MLP over
// 32-edge tiles of the SORTED edge list. Cross-iteration register prefetch of
// the h-gather; all barriers are lgkm-only so prefetch stays in flight.
// Outputs m_ij rows and coord weights to sequential slots (streaming stores).
// ---------------------------------------------------------------------------
__global__ __launch_bounds__(512, 2)
void egnn_edge_pipe_kernel(const __bf16* __restrict__ hb,
                           const int* __restrict__ srcs, const int* __restrict__ dsts,
                           const float4* __restrict__ rel4,
                           const void* __restrict__ We1, const void* __restrict__ be1,
                           const void* __restrict__ We2, const void* __restrict__ be2,
                           const void* __restrict__ Wc1, const void* __restrict__ bc1,
                           const void* __restrict__ Wc2, const int* __restrict__ flags,
                           __bf16* __restrict__ m_buf, float* __restrict__ cw_buf,
                           int Ee)
{
    const bool f32 = flags[0] != 0;
    const int tid  = threadIdx.x;
    const int wv   = tid >> 6;
    const int lane = tid & 63;
    const int quad = lane >> 4;
    const int l15  = lane & 15;
    const int mg   = wv >> 2;
    const int ng   = wv & 3;

    // persistent weight B-fragments (N=32 slice per wave)
    bf8_t bW1[8][2];
    bf8_t bW2[4][2];
    bf8_t bWc[4][2];
    float be1v[2], be2v[2], bc1v[2], w1dv[2], wc2v[2];
    #pragma unroll
    for (int t = 0; t < 2; ++t) {
        const int n = ng*32 + t*16 + l15;
        #pragma unroll
        for (int kc = 0; kc < 8; ++kc) {
            bf8_t v;
            #pragma unroll
            for (int j = 0; j < 8; ++j) v[j] = (__bf16)wload(We1, (kc*32 + quad*8 + j)*H + n, f32);
            bW1[kc][t] = v;
        }
        #pragma unroll
        for (int kc = 0; kc < 4; ++kc) {
            bf8_t v, u;
            #pragma unroll
            for (int j = 0; j < 8; ++j) {
                v[j] = (__bf16)wload(We2, (kc*32 + quad*8 + j)*H + n, f32);
                u[j] = (__bf16)wload(Wc1, (kc*32 + quad*8 + j)*H + n, f32);
            }
            bW2[kc][t] = v;
            bWc[kc][t] = u;
        }
        be1v[t] = wload(be1, n, f32);
        be2v[t] = wload(be2, n, f32);
        bc1v[t] = wload(bc1, n, f32);
        w1dv[t] = wload(We1, 256*H + n, f32);
        wc2v[t] = wload(Wc2, n, f32);
    }

    __shared__ __bf16 s_in[2][32*264];
    __shared__ __bf16 s_m1[32*136];
    __shared__ __bf16 s_m2[32*136];
    __shared__ float  s_dist[32];
    __shared__ float  s_cw[32*4];

    const int tiles = Ee >> 5;
    const int m0   = tid >> 5;        // 0..15 (thread also covers row m0+16)
    const int c0   = tid & 31;        // chunk: <16 -> h[src], >=16 -> h[dst]
    const int coff = (c0 & 15) * 8;

    bf8_t p0v, p1v;
    {   // prologue prefetch for first tile
        const int tt = (blockIdx.x < tiles) ? blockIdx.x : 0;
        const int eA = tt*32 + m0, eB = eA + 16;
        const int nA = (c0 < 16) ? srcs[eA] : dsts[eA];
        const int nB = (c0 < 16) ? srcs[eB] : dsts[eB];
        p0v = *(const bf8_t*)(hb + (size_t)nA*H + coff);
        p1v = *(const bf8_t*)(hb + (size_t)nB*H + coff);
    }

    int li = 0;
    for (int t = blockIdx.x; t < tiles; t += gridDim.x, ++li) {
        const int buf = li & 1;
        // commit prefetched gather into this iteration's buffer
        *(bf8_t*)&s_in[buf][m0*264 + c0*8]      = p0v;
        *(bf8_t*)&s_in[buf][(m0+16)*264 + c0*8] = p1v;
        if (tid < 32) s_dist[tid] = rel4[t*32 + tid].w;
        // issue next tile's gather NOW; consumed at next loop-top ds_write.
        {
            const int tn = t + gridDim.x;
            const int tt = (tn < tiles) ? tn : 0;
            const int eA = tt*32 + m0, eB = eA + 16;
            const int nA = (c0 < 16) ? srcs[eA] : dsts[eA];
            const int nB = (c0 < 16) ? srcs[eB] : dsts[eB];
            p0v = *(const bf8_t*)(hb + (size_t)nA*H + coff);
            p1v = *(const bf8_t*)(hb + (size_t)nB*H + coff);
        }
        bar_lds();

        // layer 1: silu([h_src|h_dst] @ We1 + d2*We1[256] + be1)
        {
            f4_t a0 = {0.f,0.f,0.f,0.f}, a1 = {0.f,0.f,0.f,0.f};
            const int abase = (mg*16 + l15)*264 + quad*8;
            #pragma unroll
            for (int kc = 0; kc < 8; ++kc) {
                const bf8_t a = *(const bf8_t*)&s_in[buf][abase + kc*32];
                a0 = MFMA16(a, bW1[kc][0], a0);
                a1 = MFMA16(a, bW1[kc][1], a1);
            }
            #pragma unroll
            for (int i = 0; i < 4; ++i) {
                const int m = mg*16 + quad*4 + i;
                const float d2 = s_dist[m];
                s_m1[m*136 + ng*32 + l15]      = (__bf16)silu_f(a0[i] + d2*w1dv[0] + be1v[0]);
                s_m1[m*136 + ng*32 + 16 + l15] = (__bf16)silu_f(a1[i] + d2*w1dv[1] + be1v[1]);
            }
        }
        bar_lds();

        // layer 2: m_ij = silu(m1 @ We2 + be2)
        {
            f4_t a0 = {0.f,0.f,0.f,0.f}, a1 = {0.f,0.f,0.f,0.f};
            const int abase = (mg*16 + l15)*136 + quad*8;
            #pragma unroll
            for (int kc = 0; kc < 4; ++kc) {
                const bf8_t a = *(const bf8_t*)&s_m1[abase + kc*32];
                a0 = MFMA16(a, bW2[kc][0], a0);
                a1 = MFMA16(a, bW2[kc][1], a1);
            }
            #pragma unroll
            for (int i = 0; i < 4; ++i) {
                const int m = mg*16 + quad*4 + i;
                s_m2[m*136 + ng*32 + l15]      = (__bf16)silu_f(a0[i] + be2v[0]);
                s_m2[m*136 + ng*32 + 16 + l15] = (__bf16)silu_f(a1[i] + be2v[1]);
            }
        }
        bar_lds();

        // streaming m_ij store: sorted slot == loop index -> fully sequential
        {
            const int ms = tid >> 4, cs = tid & 15;
            *(bf8_t*)(m_buf + (size_t)(t*32 + ms)*H + cs*8) = *(const bf8_t*)&s_m2[ms*136 + cs*8];
        }

        // layer 3: coord head
        {
            f4_t a0 = {0.f,0.f,0.f,0.f}, a1 = {0.f,0.f,0.f,0.f};
            const int abase = (mg*16 + l15)*136 + quad*8;
            #pragma unroll
            for (int kc = 0; kc < 4; ++kc) {
                const bf8_t a = *(const bf8_t*)&s_m2[abase + kc*32];
                a0 = MFMA16(a, bWc[kc][0], a0);
                a1 = MFMA16(a, bWc[kc][1], a1);
            }
            float p[4];
            #pragma unroll
            for (int i = 0; i < 4; ++i) {
                const float v0 = silu_f(a0[i] + bc1v[0]);
                const float v1 = silu_f(a1[i] + bc1v[1]);
                p[i] = v0*wc2v[0] + v1*wc2v[1];
            }
            #pragma unroll
            for (int off = 1; off < 16; off <<= 1) {
                #pragma unroll
                for (int i = 0; i < 4; ++i) p[i] += __shfl_xor(p[i], off, 64);
            }
            if (l15 == 0) {
                #pragma unroll
                for (int i = 0; i < 4; ++i)
                    s_cw[(mg*16 + quad*4 + i)*4 + ng] = p[i];
            }
        }
        bar_lds();

        if (tid < 32)
            cw_buf[t*32 + tid] = s_cw[tid*4] + s_cw[tid*4+1] + s_cw[tid*4+2] + s_cw[tid*4+3];
    }
}

// ---------------------------------------------------------------------------
// Aggregation: one wave per node, sequential read of sorted m_buf/cw/rel4.
// Writes msg_agg (f32) and x_out. No atomics.
// ---------------------------------------------------------------------------
__global__ __launch_bounds__(512)
void egnn_agg_kernel(const void* __restrict__ x, const int* __restrict__ off,
                     const __bf16* __restrict__ m_buf, const float* __restrict__ cw_buf,
                     const float4* __restrict__ rel4, float* __restrict__ msg_agg,
                     const int* __restrict__ flags, void* __restrict__ out,
                     size_t obase, int Nn)
{
    const bool f32 = flags[0] != 0;
    const int wv = threadIdx.x >> 6, lane = threadIdx.x & 63;
    const int n = blockIdx.x*8 + wv;
    if (n >= Nn) return;
    const int p0 = off[n], p1 = off[n+1];

    float ms0 = 0.f, ms1 = 0.f, c0 = 0.f, c1 = 0.f, c2 = 0.f;
    const unsigned int* mb = (const unsigned int*)m_buf;
    for (int p = p0; p < p1; ++p) {
        const unsigned int u = mb[(size_t)p*64 + lane];
        ms0 += __uint_as_float(u << 16);
        ms1 += __uint_as_float(u & 0xffff0000u);
        const float4 r = rel4[p];
        const float cw = cw_buf[p];
        c0 += r.x*cw; c1 += r.y*cw; c2 += r.z*cw;
    }
    float2 st; st.x = ms0; st.y = ms1;
    *(float2*)&msg_agg[(size_t)n*H + 2*lane] = st;
    if (lane == 0) {
        float xd0, xd1, xd2;
        if (f32) { const float* xp = (const float*)x + (size_t)n*3; xd0=xp[0]; xd1=xp[1]; xd2=xp[2]; }
        else     { const __bf16* xp = (const __bf16*)x + (size_t)n*3; xd0=(float)xp[0]; xd1=(float)xp[1]; xd2=(float)xp[2]; }
        const float o0 = xd0 + c0, o1 = xd1 + c1, o2 = xd2 + c2;
        if (f32) {
            float* op = (float*)out + obase + (size_t)n*3;
            op[0] = o0; op[1] = o1; op[2] = o2;
        } else {
            __bf16* op = (__bf16*)out + obase + (size_t)n*3;
            op[0] = (__bf16)o0; op[1] = (__bf16)o1; op[2] = (__bf16)o2;
        }
    }
}

// ---------------------------------------------------------------------------
// Node kernel: h_out = h + silu([h | msg_agg] @ Wn1 + bn1) @ Wn2 + bn2
// ---------------------------------------------------------------------------
__global__ __launch_bounds__(512, 2)
void egnn_node_kernel(const void* __restrict__ h, const float* __restrict__ msg_agg,
                      const void* __restrict__ Wn1, const void* __restrict__ bn1,
                      const void* __restrict__ Wn2, const void* __restrict__ bn2,
                      const int* __restrict__ flags, void* __restrict__ h_out, int Nn)
{
    const bool f32 = flags[0] != 0;
    const int tid  = threadIdx.x;
    const int wv   = tid >> 6;
    const int lane = tid & 63;
    const int quad = lane >> 4;
    const int l15  = lane & 15;
    const int mg   = wv >> 2;
    const int ng   = wv & 3;

    bf8_t bW1[8][2];
    bf8_t bW2[4][2];
    float b1v[2], b2v[2];
    #pragma unroll
    for (int t = 0; t < 2; ++t) {
        const int n = ng*32 + t*16 + l15;
        #pragma unroll
        for (int kc = 0; kc < 8; ++kc) {
            bf8_t v;
            #pragma unroll
            for (int j = 0; j < 8; ++j) v[j] = (__bf16)wload(Wn1, (kc*32 + quad*8 + j)*H + n, f32);
            bW1[kc][t] = v;
        }
        #pragma unroll
        for (int kc = 0; kc < 4; ++kc) {
            bf8_t v;
            #pragma unroll
            for (int j = 0; j < 8; ++j) v[j] = (__bf16)wload(Wn2, (kc*32 + quad*8 + j)*H + n, f32);
            bW2[kc][t] = v;
        }
        b1v[t] = wload(bn1, n, f32);
        b2v[t] = wload(bn2, n, f32);
    }

    __shared__ __bf16 s_in[32*264];
    __shared__ __bf16 s_t1[32*136];

    const int tiles = (Nn + 31) >> 5;
    for (int tile = blockIdx.x; tile < tiles; tile += gridDim.x) {
        const int nb = tile << 5;
        __syncthreads();
        #pragma unroll
        for (int r = 0; r < 2; ++r) {
            const int idx = tid + r*512;
            const int m = idx >> 5, c = idx & 31;
            int node = nb + m;
            if (node >= Nn) node = Nn - 1;
            if (c < 16) {
                *(bf8_t*)&s_in[m*264 + c*8] = hload8(h, (size_t)node*H + c*8, f32);
            } else {
                const float4* mp = (const float4*)(msg_agg + (size_t)node*H + (c - 16)*8);
                const float4 v0 = mp[0], v1 = mp[1];
                __bf16* d = &s_in[m*264 + c*8];
                d[0] = (__bf16)v0.x; d[1] = (__bf16)v0.y; d[2] = (__bf16)v0.z; d[3] = (__bf16)v0.w;
                d[4] = (__bf16)v1.x; d[5] = (__bf16)v1.y; d[6] = (__bf16)v1.z; d[7] = (__bf16)v1.w;
            }
        }
        __syncthreads();

        {
            f4_t a0 = {0.f,0.f,0.f,0.f}, a1 = {0.f,0.f,0.f,0.f};
            const int abase = (mg*16 + l15)*264 + quad*8;
            #pragma unroll
            for (int kc = 0; kc < 8; ++kc) {
                const bf8_t a = *(const bf8_t*)&s_in[abase + kc*32];
                a0 = MFMA16(a, bW1[kc][0], a0);
                a1 = MFMA16(a, bW1[kc][1], a1);
            }
            #pragma unroll
            for (int i = 0; i < 4; ++i) {
                const int m = mg*16 + quad*4 + i;
                s_t1[m*136 + ng*32 + l15]      = (__bf16)silu_f(a0[i] + b1v[0]);
                s_t1[m*136 + ng*32 + 16 + l15] = (__bf16)silu_f(a1[i] + b1v[1]);
            }
        }
        __syncthreads();

        {
            f4_t a0 = {0.f,0.f,0.f,0.f}, a1 = {0.f,0.f,0.f,0.f};
            const int abase = (mg*16 + l15)*136 + quad*8;
            #pragma unroll
            for (int kc = 0; kc < 4; ++kc) {
                const bf8_t a = *(const bf8_t*)&s_t1[abase + kc*32];
                a0 = MFMA16(a, bW2[kc][0], a0);
                a1 = MFMA16(a, bW2[kc][1], a1);
            }
            #pragma unroll
            for (int i = 0; i < 4; ++i) {
                const int node = nb + mg*16 + quad*4 + i;
                if (node < Nn) {
                    const int n0 = ng*32 + l15, n1 = n0 + 16;
                    const size_t i0 = (size_t)node*H + n0, i1 = (size_t)node*H + n1;
                    const float h0 = f32 ? ((const float*)h)[i0] : (float)((const __bf16*)h)[i0];
                    const float h1 = f32 ? ((const float*)h)[i1] : (float)((const __bf16*)h)[i1];
                    const float o0 = a0[i] + b2v[0] + h0;
                    const float o1 = a1[i] + b2v[1] + h1;
                    if (f32) {
                        ((float*)h_out)[i0] = o0;
                        ((float*)h_out)[i1] = o1;
                    } else {
                        ((__bf16*)h_out)[i0] = (__bf16)o0;
                        ((__bf16*)h_out)[i1] = (__bf16)o1;
                    }
                }
            }
        }
    }
}

// ---------------------------------------------------------------------------
// Fallback (R2 atomic path) pieces
// ---------------------------------------------------------------------------
__global__ __launch_bounds__(512, 2)
void egnn_edge_kernel(const void* __restrict__ h, const void* __restrict__ x,
                      const int* __restrict__ ei,
                      const void* __restrict__ We1, const void* __restrict__ be1,
                      const void* __restrict__ We2, const void* __restrict__ be2,
                      const void* __restrict__ Wc1, const void* __restrict__ bc1,
                      const void* __restrict__ Wc2, const int* __restrict__ flags,
                      float* __restrict__ msg_agg, float* __restrict__ coord_agg,
                      int Nn, int Ee)
{
    const bool f32 = flags[0] != 0;
    const int tid  = threadIdx.x;
    const int wv   = tid >> 6;
    const int lane = tid & 63;
    const int quad = lane >> 4;
    const int l15  = lane & 15;
    const int mg   = wv >> 2;
    const int ng   = wv & 3;

    bf8_t bW1[8][2];
    bf8_t bW2[4][2];
    bf8_t bWc[4][2];
    float be1v[2], be2v[2], bc1v[2], w1dv[2], wc2v[2];
    #pragma unroll
    for (int t = 0; t < 2; ++t) {
        const int n = ng*32 + t*16 + l15;
        #pragma unroll
        for (int kc = 0; kc < 8; ++kc) {
            bf8_t v;
            #pragma unroll
            for (int j = 0; j < 8; ++j) v[j] = (__bf16)wload(We1, (kc*32 + quad*8 + j)*H + n, f32);
            bW1[kc][t] = v;
        }
        #pragma unroll
        for (int kc = 0; kc < 4; ++kc) {
            bf8_t v, u;
            #pragma unroll
            for (int j = 0; j < 8; ++j) {
                v[j] = (__bf16)wload(We2, (kc*32 + quad*8 + j)*H + n, f32);
                u[j] = (__bf16)wload(Wc1, (kc*32 + quad*8 + j)*H + n, f32);
            }
            bW2[kc][t] = v;
            bWc[kc][t] = u;
        }
        be1v[t] = wload(be1, n, f32);
        be2v[t] = wload(be2, n, f32);
        bc1v[t] = wload(bc1, n, f32);
        w1dv[t] = wload(We1, 256*H + n, f32);
        wc2v[t] = wload(Wc2, n, f32);
    }

    __shared__ __bf16 s_in[32*264];
    __shared__ __bf16 s_m1[32*136];
    __shared__ __bf16 s_m2[32*136];
    __shared__ float  s_rel[32*3];
    __shared__ float  s_dist[32];
    __shared__ int    s_dstv[32];
    __shared__ float  s_cw[32*4];

    const int tiles = Ee >> 5;
    for (int tile = blockIdx.x; tile < tiles; tile += gridDim.x) {
        const int ebase = tile << 5;
        __syncthreads();

        if (tid < 32) {
            const int e  = ebase + tid;
            const int sn = ei[e];
            const int dn = ei[Ee + e];
            s_dstv[tid] = dn;
            float d2 = 0.f;
            #pragma unroll
            for (int c = 0; c < 3; ++c) {
                float r;
                if (f32) r = ((const float*)x)[sn*3 + c] - ((const float*)x)[dn*3 + c];
                else     r = (float)((const __bf16*)x)[sn*3 + c] - (float)((const __bf16*)x)[dn*3 + c];
                s_rel[tid*3 + c] = r;
                d2 += r*r;
            }
            s_dist[tid] = d2;
        }
        #pragma unroll
        for (int r = 0; r < 2; ++r) {
            const int idx = tid + r*512;
            const int m = idx >> 5, c = idx & 31;
            const int e = ebase + m;
            const int node = (c < 16) ? ei[e] : ei[Ee + e];
            *(bf8_t*)&s_in[m*264 + c*8] = hload8(h, (size_t)node*H + (c & 15)*8, f32);
        }
        __syncthreads();

        {
            f4_t a0 = {0.f,0.f,0.f,0.f}, a1 = {0.f,0.f,0.f,0.f};
            const int abase = (mg*16 + l15)*264 + quad*8;
            #pragma unroll
            for (int kc = 0; kc < 8; ++kc) {
                const bf8_t a = *(const bf8_t*)&s_in[abase + kc*32];
                a0 = MFMA16(a, bW1[kc][0], a0);
                a1 = MFMA16(a, bW1[kc][1], a1);
            }
            #pragma unroll
            for (int i = 0; i < 4; ++i) {
                const int m = mg*16 + quad*4 + i;
                const float d2 = s_dist[m];
                s_m1[m*136 + ng*32 + l15]      = (__bf16)silu_f(a0[i] + d2*w1dv[0] + be1v[0]);
                s_m1[m*136 + ng*32 + 16 + l15] = (__bf16)silu_f(a1[i] + d2*w1dv[1] + be1v[1]);
            }
        }
        __syncthreads();

        {
            f4_t a0 = {0.f,0.f,0.f,0.f}, a1 = {0.f,0.f,0.f,0.f};
            const int abase = (mg*16 + l15)*136 + quad*8;
            #pragma unroll
            for (int kc = 0; kc < 4; ++kc) {
                const bf8_t a = *(const bf8_t*)&s_m1[abase + kc*32];
                a0 = MFMA16(a, bW2[kc][0], a0);
                a1 = MFMA16(a, bW2[kc][1], a1);
            }
            #pragma unroll
            for (int i = 0; i < 4; ++i) {
                const int m = mg*16 + quad*4 + i;
                const float v0 = silu_f(a0[i] + be2v[0]);
                const float v1 = silu_f(a1[i] + be2v[1]);
                s_m2[m*136 + ng*32 + l15]      = (__bf16)v0;
                s_m2[m*136 + ng*32 + 16 + l15] = (__bf16)v1;
                const size_t db = (size_t)s_dstv[m]*H + ng*32 + l15;
                atomicAdd(&msg_agg[db],      v0);
                atomicAdd(&msg_agg[db + 16], v1);
            }
        }
        __syncthreads();

        {
            f4_t a0 = {0.f,0.f,0.f,0.f}, a1 = {0.f,0.f,0.f,0.f};
            const int abase = (mg*16 + l15)*136 + quad*8;
            #pragma unroll
            for (int kc = 0; kc < 4; ++kc) {
                const bf8_t a = *(const bf8_t*)&s_m2[abase + kc*32];
                a0 = MFMA16(a, bWc[kc][0], a0);
                a1 = MFMA16(a, bWc[kc][1], a1);
            }
            float p[4];
            #pragma unroll
            for (int i = 0; i < 4; ++i) {
                const float v0 = silu_f(a0[i] + bc1v[0]);
                const float v1 = silu_f(a1[i] + bc1v[1]);
                p[i] = v0*wc2v[0] + v1*wc2v[1];
            }
            #pragma unroll
            for (int off = 1; off < 16; off <<= 1) {
                #pragma unroll
                for (int i = 0; i < 4; ++i) p[i] += __shfl_xor(p[i], off, 64);
            }
            if (l15 == 0) {
                #pragma unroll
                for (int i = 0; i < 4; ++i)
                    s_cw[(mg*16 + quad*4 + i)*4 + ng] = p[i];
            }
        }
        __syncthreads();

        if (tid < 96) {
            const int m = tid / 3, c = tid - m*3;
            const float cw = s_cw[m*4 + 0] + s_cw[m*4 + 1] + s_cw[m*4 + 2] + s_cw[m*4 + 3];
            atomicAdd(&coord_agg[(size_t)s_dstv[m]*3 + c], s_rel[m*3 + c]*cw);
        }
    }
}

__global__ void egnn_x_kernel(const void* __restrict__ x, const float* __restrict__ coord_agg,
                              const int* __restrict__ flags, void* __restrict__ out,
                              size_t obase, int total)
{
    const bool f32 = flags[0] != 0;
    const int i = blockIdx.x*blockDim.x + threadIdx.x;
    if (i >= total) return;
    const float xv = f32 ? ((const float*)x)[i] : (float)((const __bf16*)x)[i];
    const float o = xv + coord_agg[i];
    if (f32) ((float*)out)[obase + i] = o;
    else     ((__bf16*)out)[obase + i] = (__bf16)o;
}

static inline size_t align256(size_t v) { return (v + 255) & ~(size_t)255; }

extern "C" void kernel_launch(void* const* d_in, const int* in_sizes, int n_in,
                              void* d_out, int out_size, void* d_ws, size_t ws_size,
                              hipStream_t stream)
{
    const void* h   = d_in[0];
    const void* x   = d_in[1];
    const void* ei0 = d_in[2];
    const void* We1 = d_in[3];
    const void* be1 = d_in[4];
    const void* We2 = d_in[5];
    const void* be2 = d_in[6];
    const void* Wc1 = d_in[7];
    const void* bc1 = d_in[8];
    const void* Wc2 = d_in[9];
    const void* Wn1 = d_in[10];
    const void* bn1 = d_in[11];
    const void* Wn2 = d_in[12];
    const void* bn2 = d_in[13];

    const int Nn = in_sizes[0] / H;   // 50000
    const int Ee = in_sizes[2] / 2;   // 640000

    char* ws = (char*)d_ws;
    size_t o = 0;
    size_t o_mbuf  = o; o = align256(o + (size_t)Ee*H*2);
    size_t o_msg   = o; o = align256(o + (size_t)Nn*H*4);
    size_t o_ei    = o; o = align256(o + (size_t)2*Ee*4);
    size_t o_srcs  = o; o = align256(o + (size_t)Ee*4);
    size_t o_dsts  = o; o = align256(o + (size_t)Ee*4);
    size_t o_cw    = o; o = align256(o + (size_t)Ee*4);
    size_t o_rel   = o; o = align256(o + (size_t)Ee*16);
    size_t o_hb    = o; o = align256(o + (size_t)Nn*H*2);
    size_t o_cnt   = o; o = align256(o + (size_t)Nn*4);
    size_t o_off   = o; o = align256(o + (size_t)(Nn+1)*4);
    size_t o_cur   = o; o = align256(o + (size_t)Nn*4);
    size_t o_bsum  = o; o = align256(o + 512*4);
    size_t o_base  = o; o = align256(o + 512*4);
    size_t o_flags = o; o = align256(o + 64);
    const size_t need_csr = o;

    const int nCh = (Nn + 1 + 511) / 512;

    if (ws_size >= need_csr) {
        __bf16* m_buf   = (__bf16*)(ws + o_mbuf);
        float*  msg_agg = (float*) (ws + o_msg);
        int*    ei      = (int*)   (ws + o_ei);
        int*    srcs    = (int*)   (ws + o_srcs);
        int*    dsts    = (int*)   (ws + o_dsts);
        float*  cw_buf  = (float*) (ws + o_cw);
        float4* rel4    = (float4*)(ws + o_rel);
        __bf16* hb      = (__bf16*)(ws + o_hb);
        int*    cnt     = (int*)   (ws + o_cnt);
        int*    off     = (int*)   (ws + o_off);
        int*    cursor  = (int*)   (ws + o_cur);
        int*    bsum    = (int*)   (ws + o_bsum);
        int*    base    = (int*)   (ws + o_base);
        int*    flags   = (int*)   (ws + o_flags);

        detect_kernel<<<1, 256, 0, stream>>>((const unsigned short*)h, (const int*)ei0, flags);
        cvt_ei_kernel<<<(2*Ee + 511)/512, 512, 0, stream>>>(ei0, ei, 2*Ee, flags);
        cvt_h_kernel<<<((Nn*H/8) + 511)/512, 512, 0, stream>>>(h, hb, flags, Nn*H/8);
        hipMemsetAsync(cnt, 0, (size_t)Nn*4, stream);
        hist_kernel<<<(Ee + 511)/512, 512, 0, stream>>>(ei, cnt, Ee);
        scanA_kernel<<<nCh, 512, 0, stream>>>(cnt, bsum, Nn);
        scanB_kernel<<<1, 64, 0, stream>>>(bsum, base, nCh);
        scanC_kernel<<<nCh, 512, 0, stream>>>(cnt, base, off, cursor, Nn);
        scatter_kernel<<<(Ee + 511)/512, 512, 0, stream>>>(ei, cursor, srcs, dsts, Ee);
        prep_geom_kernel<<<(Ee + 511)/512, 512, 0, stream>>>(x, srcs, dsts, rel4, flags, Ee);

        egnn_edge_pipe_kernel<<<1024, 512, 0, stream>>>(hb, srcs, dsts, rel4,
                                                        We1, be1, We2, be2, Wc1, bc1, Wc2,
                                                        flags, m_buf, cw_buf, Ee);

        egnn_agg_kernel<<<(Nn + 7)/8, 512, 0, stream>>>(x, off, m_buf, cw_buf, rel4,
                                                        msg_agg, flags, d_out, (size_t)Nn*H, Nn);
        egnn_node_kernel<<<512, 512, 0, stream>>>(h, msg_agg, Wn1, bn1, Wn2, bn2,
                                                  flags, d_out, Nn);
    } else {
        float* msg_agg   = (float*)ws;
        float* coord_agg = (float*)(ws + (size_t)Nn*H*4);
        int*   ei        = (int*)  (ws + (size_t)Nn*H*4 + (size_t)Nn*3*4);
        int*   flags     = (int*)  (ws + (size_t)Nn*H*4 + (size_t)Nn*3*4 + (size_t)2*Ee*4);

        detect_kernel<<<1, 256, 0, stream>>>((const unsigned short*)h, (const int*)ei0, flags);
        cvt_ei_kernel<<<(2*Ee + 255)/256, 256, 0, stream>>>(ei0, ei, 2*Ee, flags);
        hipMemsetAsync(msg_agg,   0, (size_t)Nn*H*4, stream);
        hipMemsetAsync(coord_agg, 0, (size_t)Nn*3*4, stream);
        egnn_edge_kernel<<<1024, 512, 0, stream>>>(h, x, ei, We1, be1, We2, be2,
                                                   Wc1, bc1, Wc2, flags,
                                                   msg_agg, coord_agg, Nn, Ee);
        egnn_node_kernel<<<512, 512, 0, stream>>>(h, msg_agg, Wn1, bn1, Wn2, bn2,
                                                  flags, d_out, Nn);
        egnn_x_kernel<<<(Nn*3 + 255)/256, 256, 0, stream>>>(x, coord_agg, flags, d_out,
                                                            (size_t)Nn*H, Nn*3);
    }
}

// Round 5
// 686.425 us; speedup vs baseline: 1.7477x; 1.2539x over previous
//
#include <hip/hip_runtime.h>

#define H 128

typedef __bf16 bf8_t __attribute__((ext_vector_type(8)));
typedef float  f4_t  __attribute__((ext_vector_type(4)));

#define MFMA16(a, b, c) __builtin_amdgcn_mfma_f32_16x16x32_bf16((a), (b), (c), 0, 0, 0)

__device__ __forceinline__ float silu_f(float v) {
    return v * (1.0f / (1.0f + __expf(-v)));
}

// LDS-only barrier: does NOT drain vmcnt, so global prefetch stays in flight.
__device__ __forceinline__ void bar_lds() {
    asm volatile("s_waitcnt lgkmcnt(0)\ns_barrier" ::: "memory");
}

__device__ __forceinline__ float wload(const void* p, int idx, bool f32) {
    return f32 ? ((const float*)p)[idx] : (float)((const __bf16*)p)[idx];
}

__device__ __forceinline__ bf8_t hload8(const void* p, size_t off, bool f32) {
    bf8_t v;
    if (f32) {
        const float4* q = (const float4*)((const float*)p + off);
        const float4 a = q[0], b = q[1];
        v[0]=(__bf16)a.x; v[1]=(__bf16)a.y; v[2]=(__bf16)a.z; v[3]=(__bf16)a.w;
        v[4]=(__bf16)b.x; v[5]=(__bf16)b.y; v[6]=(__bf16)b.z; v[7]=(__bf16)b.w;
    } else {
        v = *(const bf8_t*)((const __bf16*)p + off);
    }
    return v;
}

__device__ __forceinline__ int eidx(const void* ei, int i, bool i64) {
    return i64 ? (int)((const long long*)ei)[i] : ((const int*)ei)[i];
}

// ---------------------------------------------------------------------------
// dtype detection
// ---------------------------------------------------------------------------
__global__ void detect_kernel(const unsigned short* __restrict__ hraw,
                              const int* __restrict__ eiraw, int* __restrict__ flags)
{
    __shared__ int s_nf, s_oddnz;
    if (threadIdx.x == 0) { s_nf = 0; s_oddnz = 0; }
    __syncthreads();
    int nf = 0;
    for (int i = threadIdx.x; i < 16384; i += blockDim.x) {
        const unsigned short u = hraw[i];
        if (((u >> 7) & 0xFF) == 0xFF) nf++;
    }
    int onz = 0;
    for (int i = threadIdx.x; i < 512; i += blockDim.x) {
        if (eiraw[2*i + 1] != 0) onz++;
    }
    if (nf)  atomicAdd(&s_nf, nf);
    if (onz) atomicAdd(&s_oddnz, onz);
    __syncthreads();
    if (threadIdx.x == 0) {
        flags[0] = (s_nf > 0) ? 1 : 0;
        flags[1] = (s_oddnz == 0) ? 1 : 0;
    }
}

// ---------------------------------------------------------------------------
// CSR build: dst histogram (raw ei) -> scan -> scatter+geometry (fused)
// ---------------------------------------------------------------------------
__global__ void histd_kernel(const void* __restrict__ ei, int* __restrict__ cnt,
                             const int* __restrict__ flags, int Ee)
{
    const int e = blockIdx.x*blockDim.x + threadIdx.x;
    if (e < Ee) atomicAdd(&cnt[eidx(ei, Ee + e, flags[1] != 0)], 1);
}

__global__ void scanA_kernel(const int* __restrict__ cnt, int* __restrict__ bsum, int Nn)
{
    __shared__ int s[512];
    const int gi = blockIdx.x*512 + threadIdx.x;
    s[threadIdx.x] = (gi < Nn) ? cnt[gi] : 0;
    __syncthreads();
    for (int off = 256; off > 0; off >>= 1) {
        if (threadIdx.x < off) s[threadIdx.x] += s[threadIdx.x + off];
        __syncthreads();
    }
    if (threadIdx.x == 0) bsum[blockIdx.x] = s[0];
}

__global__ void scanB_kernel(int* __restrict__ bsum, int* __restrict__ base, int nCh)
{
    if (threadIdx.x == 0) {
        int acc = 0;
        for (int b = 0; b < nCh; ++b) { base[b] = acc; acc += bsum[b]; }
    }
}

__global__ void scanC_kernel(const int* __restrict__ cnt, const int* __restrict__ base,
                             int* __restrict__ off, int* __restrict__ cursor, int Nn)
{
    __shared__ int s[512];
    const int i  = threadIdx.x;
    const int gi = blockIdx.x*512 + i;
    const int v  = (gi < Nn) ? cnt[gi] : 0;
    s[i] = v;
    __syncthreads();
    for (int o = 1; o < 512; o <<= 1) {
        const int t = (i >= o) ? s[i - o] : 0;
        __syncthreads();
        s[i] += t;
        __syncthreads();
    }
    const int excl = s[i] - v;
    if (gi <= Nn) {
        const int val = base[blockIdx.x] + excl;
        off[gi] = val;
        if (gi < Nn) cursor[gi] = val;
    }
}

// scatter + geometry: compute sorted slot, write srcs/dsts/d2 at slot
__global__ void scatgeo_kernel(const void* __restrict__ ei, int* __restrict__ cursor,
                               int* __restrict__ srcs, int* __restrict__ dsts,
                               float* __restrict__ d2buf, const void* __restrict__ x,
                               const int* __restrict__ flags, int Ee)
{
    const int e = blockIdx.x*blockDim.x + threadIdx.x;
    if (e >= Ee) return;
    const bool i64 = flags[1] != 0;
    const bool f32 = flags[0] != 0;
    const int s = eidx(ei, e, i64);
    const int d = eidx(ei, Ee + e, i64);
    const int p = atomicAdd(&cursor[d], 1);
    srcs[p] = s;
    dsts[p] = d;
    float d2 = 0.f;
    #pragma unroll
    for (int c = 0; c < 3; ++c) {
        const float r = wload(x, s*3 + c, f32) - wload(x, d*3 + c, f32);
        d2 += r*r;
    }
    d2buf[p] = d2;
}

// ---------------------------------------------------------------------------
// Projection kernel: PB[n][0:128]   = (h @ We1[0:128])[n]
//                    PB[n][128:256] = (h @ We1[128:256])[n] + be1
// Node-level GEMM (50K rows) replaces the per-edge K=256 layer-1 GEMM.
// ---------------------------------------------------------------------------
__global__ __launch_bounds__(512, 2)
void proj_kernel(const void* __restrict__ h, const void* __restrict__ We1,
                 const void* __restrict__ be1, const int* __restrict__ flags,
                 __bf16* __restrict__ PB, int Nn)
{
    const bool f32 = flags[0] != 0;
    const int tid  = threadIdx.x;
    const int wv   = tid >> 6;       // 0..7 -> 32-col slice of 256
    const int lane = tid & 63;
    const int quad = lane >> 4;
    const int l15  = lane & 15;

    bf8_t bW[4][2];
    float bias[2];
    #pragma unroll
    for (int t = 0; t < 2; ++t) {
        const int n    = wv*32 + t*16 + l15;     // 0..255
        const int rb   = (n < 128) ? 0 : 128;
        const int col  = n & 127;
        #pragma unroll
        for (int kc = 0; kc < 4; ++kc) {
            bf8_t v;
            #pragma unroll
            for (int j = 0; j < 8; ++j)
                v[j] = (__bf16)wload(We1, (rb + kc*32 + quad*8 + j)*H + col, f32);
            bW[kc][t] = v;
        }
        bias[t] = (n < 128) ? 0.f : wload(be1, col, f32);
    }

    __shared__ __bf16 s_h[32*136];

    const int tiles = (Nn + 31) >> 5;
    for (int tile = blockIdx.x; tile < tiles; tile += gridDim.x) {
        const int nb = tile << 5;
        __syncthreads();
        {
            const int m = tid >> 4, c = tid & 15;
            int node = nb + m; if (node >= Nn) node = Nn - 1;
            *(bf8_t*)&s_h[m*136 + c*8] = hload8(h, (size_t)node*H + c*8, f32);
        }
        __syncthreads();

        f4_t acc[2][2];
        #pragma unroll
        for (int mm = 0; mm < 2; ++mm)
            #pragma unroll
            for (int t = 0; t < 2; ++t) acc[mm][t] = (f4_t){0.f,0.f,0.f,0.f};
        #pragma unroll
        for (int kc = 0; kc < 4; ++kc) {
            #pragma unroll
            for (int mm = 0; mm < 2; ++mm) {
                const bf8_t a = *(const bf8_t*)&s_h[(mm*16 + l15)*136 + quad*8 + kc*32];
                acc[mm][0] = MFMA16(a, bW[kc][0], acc[mm][0]);
                acc[mm][1] = MFMA16(a, bW[kc][1], acc[mm][1]);
            }
        }
        #pragma unroll
        for (int mm = 0; mm < 2; ++mm)
            #pragma unroll
            for (int i = 0; i < 4; ++i) {
                const int row = nb + mm*16 + quad*4 + i;
                if (row < Nn) {
                    #pragma unroll
                    for (int t = 0; t < 2; ++t)
                        PB[(size_t)row*256 + wv*32 + t*16 + l15] =
                            (__bf16)(acc[mm][t][i] + bias[t]);
                }
            }
    }
}

// ---------------------------------------------------------------------------
// Edge kernel v3: 64-edge dst-sorted tiles, 3 lgkm-only barriers per tile.
// Layer 1 = gather PB rows + add + d2*w1d + silu (pure VALU, staged directly).
// Layers 2/3 = register-resident-weight MFMA. 2-deep prefetch pipeline:
// indices/d2 fetched 2 tiles ahead, PB rows 1 tile ahead.
// ---------------------------------------------------------------------------
__global__ __launch_bounds__(512, 2)
void egnn_edge_pipe_kernel(const __bf16* __restrict__ PB,
                           const int* __restrict__ srcs, const int* __restrict__ dsts,
                           const float* __restrict__ d2buf,
                           const void* __restrict__ We1,  // row 256 only (w1d)
                           const void* __restrict__ We2, const void* __restrict__ be2,
                           const void* __restrict__ Wc1, const void* __restrict__ bc1,
                           const void* __restrict__ Wc2, const int* __restrict__ flags,
                           __bf16* __restrict__ m_buf, float* __restrict__ cw_buf,
                           int Ee)
{
    const bool f32 = flags[0] != 0;
    const int tid  = threadIdx.x;
    const int wv   = tid >> 6;
    const int lane = tid & 63;
    const int quad = lane >> 4;
    const int l15  = lane & 15;
    const int mg   = wv >> 2;        // 0..1: rows mg*32..+31
    const int ng   = wv & 3;         // 0..3: cols ng*32..+31

    // weights for layers 2/3 (N=32 slice per wave)
    bf8_t bW2[4][2], bWc[4][2];
    float be2v[2], bc1v[2], wc2v[2];
    #pragma unroll
    for (int t = 0; t < 2; ++t) {
        const int n = ng*32 + t*16 + l15;
        #pragma unroll
        for (int kc = 0; kc < 4; ++kc) {
            bf8_t v, u;
            #pragma unroll
            for (int j = 0; j < 8; ++j) {
                v[j] = (__bf16)wload(We2, (kc*32 + quad*8 + j)*H + n, f32);
                u[j] = (__bf16)wload(Wc1, (kc*32 + quad*8 + j)*H + n, f32);
            }
            bW2[kc][t] = v;
            bWc[kc][t] = u;
        }
        be2v[t] = wload(be2, n, f32);
        bc1v[t] = wload(bc1, n, f32);
        wc2v[t] = wload(Wc2, n, f32);
    }

    // staging role: edge row em (0..63), chunks ch and ch+8 (cols ch*8.., +64)
    const int em = tid >> 3;
    const int ch = tid & 7;
    float w1dA[8], w1dB[8];
    #pragma unroll
    for (int j = 0; j < 8; ++j) {
        w1dA[j] = wload(We1, 256*H + ch*8 + j, f32);
        w1dB[j] = wload(We1, 256*H + (ch+8)*8 + j, f32);
    }

    __shared__ __bf16 s_m1[64*136];
    __shared__ __bf16 s_m2[64*136];
    __shared__ float  s_cw[64*4];

    const int tiles = (Ee + 63) >> 6;

    // ---- pipeline prologue ----
    bf8_t rA0, rA1, rB0, rB1;   // PB rows for current tile
    float d2cur;
    int   s_n, d_n;             // indices for tile t+1 (rows issued this iter)
    float d2nxt;
    {
        int e0 = blockIdx.x*64 + em; if (e0 >= Ee) e0 = Ee - 1;
        const int sc = srcs[e0], dc = dsts[e0];
        d2cur = d2buf[e0];
        rA0 = *(const bf8_t*)(PB + (size_t)sc*256 + ch*8);
        rA1 = *(const bf8_t*)(PB + (size_t)sc*256 + (ch+8)*8);
        rB0 = *(const bf8_t*)(PB + (size_t)dc*256 + 128 + ch*8);
        rB1 = *(const bf8_t*)(PB + (size_t)dc*256 + 128 + (ch+8)*8);
        const int t1 = blockIdx.x + gridDim.x;
        const int tt = (t1 < tiles) ? t1 : blockIdx.x;
        int e1 = tt*64 + em; if (e1 >= Ee) e1 = Ee - 1;
        s_n = srcs[e1]; d_n = dsts[e1]; d2nxt = d2buf[e1];
    }

    for (int t = blockIdx.x; t < tiles; t += gridDim.x) {
        // ---- stage layer-1 output (gathered sum + silu) ----
        {
            bf8_t o0, o1;
            #pragma unroll
            for (int j = 0; j < 8; ++j) {
                const float f0 = (float)rA0[j] + (float)rB0[j] + d2cur*w1dA[j];
                const float f1 = (float)rA1[j] + (float)rB1[j] + d2cur*w1dB[j];
                o0[j] = (__bf16)silu_f(f0);
                o1[j] = (__bf16)silu_f(f1);
            }
            *(bf8_t*)&s_m1[em*136 + ch*8]       = o0;
            *(bf8_t*)&s_m1[em*136 + (ch+8)*8]   = o1;
        }
        // ---- issue PB rows for t+1; fetch indices for t+2 ----
        {
            const int sc = s_n, dc = d_n;
            rA0 = *(const bf8_t*)(PB + (size_t)sc*256 + ch*8);
            rA1 = *(const bf8_t*)(PB + (size_t)sc*256 + (ch+8)*8);
            rB0 = *(const bf8_t*)(PB + (size_t)dc*256 + 128 + ch*8);
            rB1 = *(const bf8_t*)(PB + (size_t)dc*256 + 128 + (ch+8)*8);
            d2cur = d2nxt;
            const int t2 = t + 2*gridDim.x;
            const int tt = (t2 < tiles) ? t2 : t;
            int e2 = tt*64 + em; if (e2 >= Ee) e2 = Ee - 1;
            s_n = srcs[e2]; d_n = dsts[e2]; d2nxt = d2buf[e2];
        }
        bar_lds();

        // ---- layer 2: m2 = silu(m1 @ We2 + be2) ----
        {
            f4_t a2[2][2];
            #pragma unroll
            for (int mm = 0; mm < 2; ++mm)
                #pragma unroll
                for (int h2 = 0; h2 < 2; ++h2) a2[mm][h2] = (f4_t){0.f,0.f,0.f,0.f};
            #pragma unroll
            for (int kc = 0; kc < 4; ++kc) {
                #pragma unroll
                for (int mm = 0; mm < 2; ++mm) {
                    const bf8_t a = *(const bf8_t*)&s_m1[(mg*32 + mm*16 + l15)*136 + quad*8 + kc*32];
                    a2[mm][0] = MFMA16(a, bW2[kc][0], a2[mm][0]);
                    a2[mm][1] = MFMA16(a, bW2[kc][1], a2[mm][1]);
                }
            }
            #pragma unroll
            for (int mm = 0; mm < 2; ++mm)
                #pragma unroll
                for (int i = 0; i < 4; ++i) {
                    const int m = mg*32 + mm*16 + quad*4 + i;
                    s_m2[m*136 + ng*32 + l15]      = (__bf16)silu_f(a2[mm][0][i] + be2v[0]);
                    s_m2[m*136 + ng*32 + 16 + l15] = (__bf16)silu_f(a2[mm][1][i] + be2v[1]);
                }
        }
        bar_lds();

        // ---- streaming m_ij store (sorted slot == tile-sequential) ----
        {
            const int ms = tid >> 4, c2 = tid & 15;
            *(bf8_t*)(m_buf + ((size_t)t*64 + ms)*H + c2*8) =
                *(const bf8_t*)&s_m2[ms*136 + c2*8];
            *(bf8_t*)(m_buf + ((size_t)t*64 + 32 + ms)*H + c2*8) =
                *(const bf8_t*)&s_m2[(ms+32)*136 + c2*8];
        }

        // ---- layer 3: coord head ----
        {
            f4_t a3[2][2];
            #pragma unroll
            for (int mm = 0; mm < 2; ++mm)
                #pragma unroll
                for (int h2 = 0; h2 < 2; ++h2) a3[mm][h2] = (f4_t){0.f,0.f,0.f,0.f};
            #pragma unroll
            for (int kc = 0; kc < 4; ++kc) {
                #pragma unroll
                for (int mm = 0; mm < 2; ++mm) {
                    const bf8_t a = *(const bf8_t*)&s_m2[(mg*32 + mm*16 + l15)*136 + quad*8 + kc*32];
                    a3[mm][0] = MFMA16(a, bWc[kc][0], a3[mm][0]);
                    a3[mm][1] = MFMA16(a, bWc[kc][1], a3[mm][1]);
                }
            }
            float p[2][4];
            #pragma unroll
            for (int mm = 0; mm < 2; ++mm)
                #pragma unroll
                for (int i = 0; i < 4; ++i) {
                    const float v0 = silu_f(a3[mm][0][i] + bc1v[0]);
                    const float v1 = silu_f(a3[mm][1][i] + bc1v[1]);
                    p[mm][i] = v0*wc2v[0] + v1*wc2v[1];
                }
            #pragma unroll
            for (int off = 1; off < 16; off <<= 1)
                #pragma unroll
                for (int mm = 0; mm < 2; ++mm)
                    #pragma unroll
                    for (int i = 0; i < 4; ++i) p[mm][i] += __shfl_xor(p[mm][i], off, 64);
            if (l15 == 0) {
                #pragma unroll
                for (int mm = 0; mm < 2; ++mm)
                    #pragma unroll
                    for (int i = 0; i < 4; ++i)
                        s_cw[(mg*32 + mm*16 + quad*4 + i)*4 + ng] = p[mm][i];
            }
        }
        bar_lds();

        if (tid < 64)
            cw_buf[(size_t)t*64 + tid] =
                s_cw[tid*4] + s_cw[tid*4+1] + s_cw[tid*4+2] + s_cw[tid*4+3];
    }
}

// ---------------------------------------------------------------------------
// Aggregation: one wave per node, sequential read of sorted m_buf/cw;
// rel_pos recomputed from x. Writes msg_agg (f32) and x_out. No atomics.
// ---------------------------------------------------------------------------
__global__ __launch_bounds__(512)
void egnn_agg_kernel(const void* __restrict__ x, const int* __restrict__ off,
                     const int* __restrict__ srcs, const __bf16* __restrict__ m_buf,
                     const float* __restrict__ cw_buf, float* __restrict__ msg_agg,
                     const int* __restrict__ flags, void* __restrict__ out,
                     size_t obase, int Nn)
{
    const bool f32 = flags[0] != 0;
    const int wv = threadIdx.x >> 6, lane = threadIdx.x & 63;
    const int n = blockIdx.x*8 + wv;
    if (n >= Nn) return;
    const int p0 = off[n], p1 = off[n+1];

    float xd0, xd1, xd2;
    if (f32) { const float* xp = (const float*)x + (size_t)n*3; xd0=xp[0]; xd1=xp[1]; xd2=xp[2]; }
    else     { const __bf16* xp = (const __bf16*)x + (size_t)n*3; xd0=(float)xp[0]; xd1=(float)xp[1]; xd2=(float)xp[2]; }

    float ms0 = 0.f, ms1 = 0.f, c0 = 0.f, c1 = 0.f, c2 = 0.f;
    const unsigned int* mb = (const unsigned int*)m_buf;
    for (int p = p0; p < p1; ++p) {
        const unsigned int u = mb[(size_t)p*64 + lane];
        ms0 += __uint_as_float(u << 16);
        ms1 += __uint_as_float(u & 0xffff0000u);
        const float cw = cw_buf[p];
        const int sn = srcs[p];
        float xs0, xs1, xs2;
        if (f32) { const float* xp = (const float*)x + (size_t)sn*3; xs0=xp[0]; xs1=xp[1]; xs2=xp[2]; }
        else     { const __bf16* xp = (const __bf16*)x + (size_t)sn*3; xs0=(float)xp[0]; xs1=(float)xp[1]; xs2=(float)xp[2]; }
        c0 += (xs0 - xd0)*cw;
        c1 += (xs1 - xd1)*cw;
        c2 += (xs2 - xd2)*cw;
    }
    float2 st; st.x = ms0; st.y = ms1;
    *(float2*)&msg_agg[(size_t)n*H + 2*lane] = st;
    if (lane == 0) {
        const float o0 = xd0 + c0, o1 = xd1 + c1, o2 = xd2 + c2;
        if (f32) {
            float* op = (float*)out + obase + (size_t)n*3;
            op[0] = o0; op[1] = o1; op[2] = o2;
        } else {
            __bf16* op = (__bf16*)out + obase + (size_t)n*3;
            op[0] = (__bf16)o0; op[1] = (__bf16)o1; op[2] = (__bf16)o2;
        }
    }
}

// ---------------------------------------------------------------------------
// Node kernel: h_out = h + silu([h | msg_agg] @ Wn1 + bn1) @ Wn2 + bn2
// ---------------------------------------------------------------------------
__global__ __launch_bounds__(512, 2)
void egnn_node_kernel(const void* __restrict__ h, const float* __restrict__ msg_agg,
                      const void* __restrict__ Wn1, const void* __restrict__ bn1,
                      const void* __restrict__ Wn2, const void* __restrict__ bn2,
                      const int* __restrict__ flags, void* __restrict__ h_out, int Nn)
{
    const bool f32 = flags[0] != 0;
    const int tid  = threadIdx.x;
    const int wv   = tid >> 6;
    const int lane = tid & 63;
    const int quad = lane >> 4;
    const int l15  = lane & 15;
    const int mg   = wv >> 2;
    const int ng   = wv & 3;

    bf8_t bW1[8][2];
    bf8_t bW2[4][2];
    float b1v[2], b2v[2];
    #pragma unroll
    for (int t = 0; t < 2; ++t) {
        const int n = ng*32 + t*16 + l15;
        #pragma unroll
        for (int kc = 0; kc < 8; ++kc) {
            bf8_t v;
            #pragma unroll
            for (int j = 0; j < 8; ++j) v[j] = (__bf16)wload(Wn1, (kc*32 + quad*8 + j)*H + n, f32);
            bW1[kc][t] = v;
        }
        #pragma unroll
        for (int kc = 0; kc < 4; ++kc) {
            bf8_t v;
            #pragma unroll
            for (int j = 0; j < 8; ++j) v[j] = (__bf16)wload(Wn2, (kc*32 + quad*8 + j)*H + n, f32);
            bW2[kc][t] = v;
        }
        b1v[t] = wload(bn1, n, f32);
        b2v[t] = wload(bn2, n, f32);
    }

    __shared__ __bf16 s_in[32*264];
    __shared__ __bf16 s_t1[32*136];

    const int tiles = (Nn + 31) >> 5;
    for (int tile = blockIdx.x; tile < tiles; tile += gridDim.x) {
        const int nb = tile << 5;
        __syncthreads();
        #pragma unroll
        for (int r = 0; r < 2; ++r) {
            const int idx = tid + r*512;
            const int m = idx >> 5, c = idx & 31;
            int node = nb + m;
            if (node >= Nn) node = Nn - 1;
            if (c < 16) {
                *(bf8_t*)&s_in[m*264 + c*8] = hload8(h, (size_t)node*H + c*8, f32);
            } else {
                const float4* mp = (const float4*)(msg_agg + (size_t)node*H + (c - 16)*8);
                const float4 v0 = mp[0], v1 = mp[1];
                __bf16* d = &s_in[m*264 + c*8];
                d[0] = (__bf16)v0.x; d[1] = (__bf16)v0.y; d[2] = (__bf16)v0.z; d[3] = (__bf16)v0.w;
                d[4] = (__bf16)v1.x; d[5] = (__bf16)v1.y; d[6] = (__bf16)v1.z; d[7] = (__bf16)v1.w;
            }
        }
        __syncthreads();

        {
            f4_t a0 = {0.f,0.f,0.f,0.f}, a1 = {0.f,0.f,0.f,0.f};
            const int abase = (mg*16 + l15)*264 + quad*8;
            #pragma unroll
            for (int kc = 0; kc < 8; ++kc) {
                const bf8_t a = *(const bf8_t*)&s_in[abase + kc*32];
                a0 = MFMA16(a, bW1[kc][0], a0);
                a1 = MFMA16(a, bW1[kc][1], a1);
            }
            #pragma unroll
            for (int i = 0; i < 4; ++i) {
                const int m = mg*16 + quad*4 + i;
                s_t1[m*136 + ng*32 + l15]      = (__bf16)silu_f(a0[i] + b1v[0]);
                s_t1[m*136 + ng*32 + 16 + l15] = (__bf16)silu_f(a1[i] + b1v[1]);
            }
        }
        __syncthreads();

        {
            f4_t a0 = {0.f,0.f,0.f,0.f}, a1 = {0.f,0.f,0.f,0.f};
            const int abase = (mg*16 + l15)*136 + quad*8;
            #pragma unroll
            for (int kc = 0; kc < 4; ++kc) {
                const bf8_t a = *(const bf8_t*)&s_t1[abase + kc*32];
                a0 = MFMA16(a, bW2[kc][0], a0);
                a1 = MFMA16(a, bW2[kc][1], a1);
            }
            #pragma unroll
            for (int i = 0; i < 4; ++i) {
                const int node = nb + mg*16 + quad*4 + i;
                if (node < Nn) {
                    const int n0 = ng*32 + l15, n1 = n0 + 16;
                    const size_t i0 = (size_t)node*H + n0, i1 = (size_t)node*H + n1;
                    const float h0 = f32 ? ((const float*)h)[i0] : (float)((const __bf16*)h)[i0];
                    const float h1 = f32 ? ((const float*)h)[i1] : (float)((const __bf16*)h)[i1];
                    const float o0 = a0[i] + b2v[0] + h0;
                    const float o1 = a1[i] + b2v[1] + h1;
                    if (f32) {
                        ((float*)h_out)[i0] = o0;
                        ((float*)h_out)[i1] = o1;
                    } else {
                        ((__bf16*)h_out)[i0] = (__bf16)o0;
                        ((__bf16*)h_out)[i1] = (__bf16)o1;
                    }
                }
            }
        }
    }
}

// ---------------------------------------------------------------------------
// Fallback (R2 atomic path)
// ---------------------------------------------------------------------------
__global__ void cvt_ei_kernel(const void* __restrict__ src, int* __restrict__ dst,
                              int n, const int* __restrict__ flags)
{
    const int i = blockIdx.x*blockDim.x + threadIdx.x;
    if (i >= n) return;
    dst[i] = flags[1] ? (int)((const long long*)src)[i] : ((const int*)src)[i];
}

__global__ __launch_bounds__(512, 2)
void egnn_edge_kernel(const void* __restrict__ h, const void* __restrict__ x,
                      const int* __restrict__ ei,
                      const void* __restrict__ We1, const void* __restrict__ be1,
                      const void* __restrict__ We2, const void* __restrict__ be2,
                      const void* __restrict__ Wc1, const void* __restrict__ bc1,
                      const void* __restrict__ Wc2, const int* __restrict__ flags,
                      float* __restrict__ msg_agg, float* __restrict__ coord_agg,
                      int Nn, int Ee)
{
    const bool f32 = flags[0] != 0;
    const int tid  = threadIdx.x;
    const int wv   = tid >> 6;
    const int lane = tid & 63;
    const int quad = lane >> 4;
    const int l15  = lane & 15;
    const int mg   = wv >> 2;
    const int ng   = wv & 3;

    bf8_t bW1[8][2];
    bf8_t bW2[4][2];
    bf8_t bWc[4][2];
    float be1v[2], be2v[2], bc1v[2], w1dv[2], wc2v[2];
    #pragma unroll
    for (int t = 0; t < 2; ++t) {
        const int n = ng*32 + t*16 + l15;
        #pragma unroll
        for (int kc = 0; kc < 8; ++kc) {
            bf8_t v;
            #pragma unroll
            for (int j = 0; j < 8; ++j) v[j] = (__bf16)wload(We1, (kc*32 + quad*8 + j)*H + n, f32);
            bW1[kc][t] = v;
        }
        #pragma unroll
        for (int kc = 0; kc < 4; ++kc) {
            bf8_t v, u;
            #pragma unroll
            for (int j = 0; j < 8; ++j) {
                v[j] = (__bf16)wload(We2, (kc*32 + quad*8 + j)*H + n, f32);
                u[j] = (__bf16)wload(Wc1, (kc*32 + quad*8 + j)*H + n, f32);
            }
            bW2[kc][t] = v;
            bWc[kc][t] = u;
        }
        be1v[t] = wload(be1, n, f32);
        be2v[t] = wload(be2, n, f32);
        bc1v[t] = wload(bc1, n, f32);
        w1dv[t] = wload(We1, 256*H + n, f32);
        wc2v[t] = wload(Wc2, n, f32);
    }

    __shared__ __bf16 s_in[32*264];
    __shared__ __bf16 s_m1[32*136];
    __shared__ __bf16 s_m2[32*136];
    __shared__ float  s_rel[32*3];
    __shared__ float  s_dist[32];
    __shared__ int    s_dstv[32];
    __shared__ float  s_cw[32*4];

    const int tiles = Ee >> 5;
    for (int tile = blockIdx.x; tile < tiles; tile += gridDim.x) {
        const int ebase = tile << 5;
        __syncthreads();

        if (tid < 32) {
            const int e  = ebase + tid;
            const int sn = ei[e];
            const int dn = ei[Ee + e];
            s_dstv[tid] = dn;
            float d2 = 0.f;
            #pragma unroll
            for (int c = 0; c < 3; ++c) {
                float r;
                if (f32) r = ((const float*)x)[sn*3 + c] - ((const float*)x)[dn*3 + c];
                else     r = (float)((const __bf16*)x)[sn*3 + c] - (float)((const __bf16*)x)[dn*3 + c];
                s_rel[tid*3 + c] = r;
                d2 += r*r;
            }
            s_dist[tid] = d2;
        }
        #pragma unroll
        for (int r = 0; r < 2; ++r) {
            const int idx = tid + r*512;
            const int m = idx >> 5, c = idx & 31;
            const int e = ebase + m;
            const int node = (c < 16) ? ei[e] : ei[Ee + e];
            *(bf8_t*)&s_in[m*264 + c*8] = hload8(h, (size_t)node*H + (c & 15)*8, f32);
        }
        __syncthreads();

        {
            f4_t a0 = {0.f,0.f,0.f,0.f}, a1 = {0.f,0.f,0.f,0.f};
            const int abase = (mg*16 + l15)*264 + quad*8;
            #pragma unroll
            for (int kc = 0; kc < 8; ++kc) {
                const bf8_t a = *(const bf8_t*)&s_in[abase + kc*32];
                a0 = MFMA16(a, bW1[kc][0], a0);
                a1 = MFMA16(a, bW1[kc][1], a1);
            }
            #pragma unroll
            for (int i = 0; i < 4; ++i) {
                const int m = mg*16 + quad*4 + i;
                const float d2 = s_dist[m];
                s_m1[m*136 + ng*32 + l15]      = (__bf16)silu_f(a0[i] + d2*w1dv[0] + be1v[0]);
                s_m1[m*136 + ng*32 + 16 + l15] = (__bf16)silu_f(a1[i] + d2*w1dv[1] + be1v[1]);
            }
        }
        __syncthreads();

        {
            f4_t a0 = {0.f,0.f,0.f,0.f}, a1 = {0.f,0.f,0.f,0.f};
            const int abase = (mg*16 + l15)*136 + quad*8;
            #pragma unroll
            for (int kc = 0; kc < 4; ++kc) {
                const bf8_t a = *(const bf8_t*)&s_m1[abase + kc*32];
                a0 = MFMA16(a, bW2[kc][0], a0);
                a1 = MFMA16(a, bW2[kc][1], a1);
            }
            #pragma unroll
            for (int i = 0; i < 4; ++i) {
                const int m = mg*16 + quad*4 + i;
                const float v0 = silu_f(a0[i] + be2v[0]);
                const float v1 = silu_f(a1[i] + be2v[1]);
                s_m2[m*136 + ng*32 + l15]      = (__bf16)v0;
                s_m2[m*136 + ng*32 + 16 + l15] = (__bf16)v1;
                const size_t db = (size_t)s_dstv[m]*H + ng*32 + l15;
                atomicAdd(&msg_agg[db],      v0);
                atomicAdd(&msg_agg[db + 16], v1);
            }
        }
        __syncthreads();

        {
            f4_t a0 = {0.f,0.f,0.f,0.f}, a1 = {0.f,0.f,0.f,0.f};
            const int abase = (mg*16 + l15)*136 + quad*8;
            #pragma unroll
            for (int kc = 0; kc < 4; ++kc) {
                const bf8_t a = *(const bf8_t*)&s_m2[abase + kc*32];
                a0 = MFMA16(a, bWc[kc][0], a0);
                a1 = MFMA16(a, bWc[kc][1], a1);
            }
            float p[4];
            #pragma unroll
            for (int i = 0; i < 4; ++i) {
                const float v0 = silu_f(a0[i] + bc1v[0]);
                const float v1 = silu_f(a1[i] + bc1v[1]);
                p[i] = v0*wc2v[0] + v1*wc2v[1];
            }
            #pragma unroll
            for (int off = 1; off < 16; off <<= 1) {
                #pragma unroll
                for (int i = 0; i < 4; ++i) p[i] += __shfl_xor(p[i], off, 64);
            }
            if (l15 == 0) {
                #pragma unroll
                for (int i = 0; i < 4; ++i)
                    s_cw[(mg*16 + quad*4 + i)*4 + ng] = p[i];
            }
        }
        __syncthreads();

        if (tid < 96) {
            const int m = tid / 3, c = tid - m*3;
            const float cw = s_cw[m*4 + 0] + s_cw[m*4 + 1] + s_cw[m*4 + 2] + s_cw[m*4 + 3];
            atomicAdd(&coord_agg[(size_t)s_dstv[m]*3 + c], s_rel[m*3 + c]*cw);
        }
    }
}

__global__ void egnn_x_kernel(const void* __restrict__ x, const float* __restrict__ coord_agg,
                              const int* __restrict__ flags, void* __restrict__ out,
                              size_t obase, int total)
{
    const bool f32 = flags[0] != 0;
    const int i = blockIdx.x*blockDim.x + threadIdx.x;
    if (i >= total) return;
    const float xv = f32 ? ((const float*)x)[i] : (float)((const __bf16*)x)[i];
    const float o = xv + coord_agg[i];
    if (f32) ((float*)out)[obase + i] = o;
    else     ((__bf16*)out)[obase + i] = (__bf16)o;
}

static inline size_t align256(size_t v) { return (v + 255) & ~(size_t)255; }

extern "C" void kernel_launch(void* const* d_in, const int* in_sizes, int n_in,
                              void* d_out, int out_size, void* d_ws, size_t ws_size,
                              hipStream_t stream)
{
    const void* h   = d_in[0];
    const void* x   = d_in[1];
    const void* ei0 = d_in[2];
    const void* We1 = d_in[3];
    const void* be1 = d_in[4];
    const void* We2 = d_in[5];
    const void* be2 = d_in[6];
    const void* Wc1 = d_in[7];
    const void* bc1 = d_in[8];
    const void* Wc2 = d_in[9];
    const void* Wn1 = d_in[10];
    const void* bn1 = d_in[11];
    const void* Wn2 = d_in[12];
    const void* bn2 = d_in[13];

    const int Nn = in_sizes[0] / H;   // 50000
    const int Ee = in_sizes[2] / 2;   // 640000
    const int EeP = ((Ee + 63) & ~63) + 64;   // padded slots for tile stores

    char* ws = (char*)d_ws;
    size_t o = 0;
    size_t o_mbuf  = o; o = align256(o + (size_t)EeP*H*2);     // m_ij bf16 (sorted)
    size_t o_msg   = o; o = align256(o + (size_t)Nn*H*4);      // msg_agg f32
    size_t o_srcs  = o; o = align256(o + (size_t)Ee*4);
    size_t o_dsts  = o; o = align256(o + (size_t)Ee*4);
    size_t o_cw    = o; o = align256(o + (size_t)EeP*4);
    size_t o_d2    = o; o = align256(o + (size_t)Ee*4);
    size_t o_pb    = o; o = align256(o + (size_t)Nn*256*2);    // PB bf16 [N,256]
    size_t o_cnt   = o; o = align256(o + (size_t)Nn*4);
    size_t o_off   = o; o = align256(o + (size_t)(Nn+1)*4);
    size_t o_cur   = o; o = align256(o + (size_t)Nn*4);
    size_t o_bsum  = o; o = align256(o + 512*4);
    size_t o_base  = o; o = align256(o + 512*4);
    size_t o_flags = o; o = align256(o + 64);
    const size_t need_csr = o;

    const int nCh = (Nn + 1 + 511) / 512;

    if (ws_size >= need_csr) {
        __bf16* m_buf   = (__bf16*)(ws + o_mbuf);
        float*  msg_agg = (float*) (ws + o_msg);
        int*    srcs    = (int*)   (ws + o_srcs);
        int*    dsts    = (int*)   (ws + o_dsts);
        float*  cw_buf  = (float*) (ws + o_cw);
        float*  d2buf   = (float*) (ws + o_d2);
        __bf16* PB      = (__bf16*)(ws + o_pb);
        int*    cnt     = (int*)   (ws + o_cnt);
        int*    off     = (int*)   (ws + o_off);
        int*    cursor  = (int*)   (ws + o_cur);
        int*    bsum    = (int*)   (ws + o_bsum);
        int*    base    = (int*)   (ws + o_base);
        int*    flags   = (int*)   (ws + o_flags);

        detect_kernel<<<1, 256, 0, stream>>>((const unsigned short*)h, (const int*)ei0, flags);
        hipMemsetAsync(cnt, 0, (size_t)Nn*4, stream);
        histd_kernel<<<(Ee + 511)/512, 512, 0, stream>>>(ei0, cnt, flags, Ee);
        scanA_kernel<<<nCh, 512, 0, stream>>>(cnt, bsum, Nn);
        scanB_kernel<<<1, 64, 0, stream>>>(bsum, base, nCh);
        scanC_kernel<<<nCh, 512, 0, stream>>>(cnt, base, off, cursor, Nn);
        scatgeo_kernel<<<(Ee + 511)/512, 512, 0, stream>>>(ei0, cursor, srcs, dsts,
                                                           d2buf, x, flags, Ee);
        proj_kernel<<<512, 512, 0, stream>>>(h, We1, be1, flags, PB, Nn);

        egnn_edge_pipe_kernel<<<512, 512, 0, stream>>>(PB, srcs, dsts, d2buf,
                                                       We1, We2, be2, Wc1, bc1, Wc2,
                                                       flags, m_buf, cw_buf, Ee);

        egnn_agg_kernel<<<(Nn + 7)/8, 512, 0, stream>>>(x, off, srcs, m_buf, cw_buf,
                                                        msg_agg, flags, d_out, (size_t)Nn*H, Nn);
        egnn_node_kernel<<<512, 512, 0, stream>>>(h, msg_agg, Wn1, bn1, Wn2, bn2,
                                                  flags, d_out, Nn);
    } else {
        // fallback: proven R2 atomic path
        float* msg_agg   = (float*)ws;
        float* coord_agg = (float*)(ws + (size_t)Nn*H*4);
        int*   ei        = (int*)  (ws + (size_t)Nn*H*4 + (size_t)Nn*3*4);
        int*   flags     = (int*)  (ws + (size_t)Nn*H*4 + (size_t)Nn*3*4 + (size_t)2*Ee*4);

        detect_kernel<<<1, 256, 0, stream>>>((const unsigned short*)h, (const int*)ei0, flags);
        cvt_ei_kernel<<<(2*Ee + 255)/256, 256, 0, stream>>>(ei0, ei, 2*Ee, flags);
        hipMemsetAsync(msg_agg,   0, (size_t)Nn*H*4, stream);
        hipMemsetAsync(coord_agg, 0, (size_t)Nn*3*4, stream);
        egnn_edge_kernel<<<1024, 512, 0, stream>>>(h, x, ei, We1, be1, We2, be2,
                                                   Wc1, bc1, Wc2, flags,
                                                   msg_agg, coord_agg, Nn, Ee);
        egnn_node_kernel<<<512, 512, 0, stream>>>(h, msg_agg, Wn1, bn1, Wn2, bn2,
                                                  flags, d_out, Nn);
        egnn_x_kernel<<<(Nn*3 + 255)/256, 256, 0, stream>>>(x, coord_agg, flags, d_out,
                                                            (size_t)Nn*H, Nn*3);
    }
}